// Round 1
// baseline (1146.290 us; speedup 1.0000x reference)
//
#include <hip/hip_runtime.h>
#include <math.h>

#define LN_EPS 1e-5f

typedef short bf16x8 __attribute__((ext_vector_type(8)));
typedef float f32x4  __attribute__((ext_vector_type(4)));

__device__ __forceinline__ float gelu_f(float v) {
    return 0.5f * v * (1.0f + erff(v * 0.70710678118654752f));
}
__device__ __forceinline__ unsigned short f2bf(float f) {
    unsigned u = __float_as_uint(f);
    return (unsigned short)((u + 0x7fffu + ((u >> 16) & 1u)) >> 16);
}
__device__ __forceinline__ float bf2f(unsigned short h) {
    return __uint_as_float(((unsigned)h) << 16);
}

// ===========================================================================
// K0: swizzle MLP weights into MFMA B-fragment order, split hi/lo bf16.
// B[k][n], n = lane&15, k = (lane>>4)*8 + j.  Per tile: 128 uint4 = [hi|lo].
// ===========================================================================
__global__ __launch_bounds__(256) void k0_swizzle(
    const float* __restrict__ wW0, const float* __restrict__ wW1, const float* __restrict__ wW2,
    const float* __restrict__ hW0, const float* __restrict__ hW1, const float* __restrict__ hW2,
    uint4* __restrict__ dst)
{
    int mat = blockIdx.x;
    const float* W; int N, ntiles, base;
    switch (mat) {
      case 0: W=wW0; N=64; ntiles=8;  base=0;    break;
      case 1: W=wW1; N=64; ntiles=8;  base=1024; break;
      case 2: W=wW2; N=96; ntiles=12; base=2048; break;
      case 3: W=hW0; N=64; ntiles=8;  base=3584; break;
      case 4: W=hW1; N=64; ntiles=8;  base=4608; break;
      default:W=hW2; N=96; ntiles=12; base=5632; break;
    }
    int lane = threadIdx.x & 63;
    for (int t = threadIdx.x >> 6; t < ntiles; t += 4) {
        int nt = t >> 1, ks = t & 1;
        int n  = nt*16 + (lane & 15);
        int k0 = ks*32 + (lane >> 4)*8;
        unsigned hi[8], lo[8];
        #pragma unroll
        for (int j = 0; j < 8; ++j) {
            float v = W[(k0 + j)*N + n];
            unsigned short h = f2bf(v);
            hi[j] = h;
            lo[j] = f2bf(v - bf2f(h));
        }
        uint4 ph, pl;
        ph.x = hi[0] | (hi[1]<<16); ph.y = hi[2] | (hi[3]<<16);
        ph.z = hi[4] | (hi[5]<<16); ph.w = hi[6] | (hi[7]<<16);
        pl.x = lo[0] | (lo[1]<<16); pl.y = lo[2] | (lo[3]<<16);
        pl.z = lo[4] | (lo[5]<<16); pl.w = lo[6] | (lo[7]<<16);
        dst[base + t*128 + lane]      = ph;
        dst[base + t*128 + 64 + lane] = pl;
    }
}

// ===========================================================================
// Split-precision MFMA GEMM helper (wave-private 16 rows in LDS).
// ===========================================================================
template<int NT>
__device__ __forceinline__ void gemm64(
    const unsigned short* aHi, const unsigned short* aLo,
    const uint4* __restrict__ wsw, int tbase, int row, int quad, int lane,
    f32x4* acc)
{
    union U { uint4 u; bf16x8 b; };
    bf16x8 aH[2], aL[2];
    #pragma unroll
    for (int ks = 0; ks < 2; ++ks) {
        aH[ks] = *(const bf16x8*)&aHi[row*72 + ks*32 + quad*8];
        aL[ks] = *(const bf16x8*)&aLo[row*72 + ks*32 + quad*8];
    }
    #pragma unroll
    for (int nt = 0; nt < NT; ++nt) {
        f32x4 a = {0.f, 0.f, 0.f, 0.f};
        #pragma unroll
        for (int ks = 0; ks < 2; ++ks) {
            int t = tbase + nt*2 + ks;
            U bh, bl;
            bh.u = wsw[t*128 + lane];
            bl.u = wsw[t*128 + 64 + lane];
            a = __builtin_amdgcn_mfma_f32_16x16x32_bf16(aH[ks], bh.b, a, 0, 0, 0);
            a = __builtin_amdgcn_mfma_f32_16x16x32_bf16(aH[ks], bl.b, a, 0, 0, 0);
            a = __builtin_amdgcn_mfma_f32_16x16x32_bf16(aL[ks], bh.b, a, 0, 0, 0);
        }
        acc[nt] = a;
    }
}

__device__ __forceinline__ void ln_gelu_pass(
    f32x4* acc, const float* __restrict__ bias, const float* __restrict__ wrow,
    float coordBase, float coordScale,
    const float* __restrict__ gg, const float* __restrict__ bb,
    unsigned short* aHi, unsigned short* aLo, int rbase, int quad, int li)
{
    float vals[4][4];
    float s1[4] = {0,0,0,0}, s2[4] = {0,0,0,0};
    #pragma unroll
    for (int nt = 0; nt < 4; ++nt) {
        int col = nt*16 + li;
        float bv = bias[col];
        float br = wrow[col];
        #pragma unroll
        for (int rg = 0; rg < 4; ++rg) {
            float coord = (coordBase + (float)(rbase + quad*4 + rg)) * coordScale;
            float v = acc[nt][rg] + fmaf(coord, br, bv);
            vals[nt][rg] = v;
            s1[rg] += v;
            s2[rg] = fmaf(v, v, s2[rg]);
        }
    }
    #pragma unroll
    for (int d = 1; d < 16; d <<= 1) {
        #pragma unroll
        for (int rg = 0; rg < 4; ++rg) {
            s1[rg] += __shfl_xor(s1[rg], d, 64);
            s2[rg] += __shfl_xor(s2[rg], d, 64);
        }
    }
    #pragma unroll
    for (int nt = 0; nt < 4; ++nt) {
        int col = nt*16 + li;
        float gv = gg[col], bev = bb[col];
        #pragma unroll
        for (int rg = 0; rg < 4; ++rg) {
            float mu   = s1[rg] * 0.015625f;
            float rstd = rsqrtf(s2[rg]*0.015625f - mu*mu + LN_EPS);
            float v = gelu_f(fmaf((vals[nt][rg] - mu)*rstd, gv, bev));
            int r = rbase + quad*4 + rg;
            unsigned short hv = f2bf(v);
            aHi[r*72 + col] = hv;
            aLo[r*72 + col] = f2bf(v - bf2f(hv));
        }
    }
}

__device__ __forceinline__ void mlp_body(
    unsigned short* aHi, unsigned short* aLo,
    const uint4* __restrict__ wsw,
    const float* __restrict__ w0row,
    const float* __restrict__ b0, const float* __restrict__ g0, const float* __restrict__ be0,
    const float* __restrict__ b1, const float* __restrict__ g1, const float* __restrict__ be1,
    const float* __restrict__ b2,
    float coordBase,
    float* __restrict__ outR, float* __restrict__ outI, int pixBase)
{
    int tid = threadIdx.x;
    int wv = __builtin_amdgcn_readfirstlane(tid >> 6);
    int lane = tid & 63, li = lane & 15, quad = lane >> 4;
    int rbase = wv*16;
    int row = rbase + li;
    f32x4 acc[6];

    gemm64<4>(aHi, aLo, wsw, 0, row, quad, lane, acc);
    ln_gelu_pass(acc, b0, w0row, coordBase, 1.0f/191.0f, g0, be0, aHi, aLo, rbase, quad, li);
    gemm64<4>(aHi, aLo, wsw, 8, row, quad, lane, acc);
    ln_gelu_pass(acc, b1, b1, 0.f, 0.f, g1, be1, aHi, aLo, rbase, quad, li);
    gemm64<6>(aHi, aLo, wsw, 16, row, quad, lane, acc);
    #pragma unroll
    for (int nt = 0; nt < 6; ++nt) {
        int j = nt*16 + li;
        float bv = b2[j];
        #pragma unroll
        for (int rg = 0; rg < 4; ++rg) {
            float v = acc[nt][rg] + bv;
            int pix = pixBase + rbase + quad*4 + rg;
            if (nt < 3) outR[pix*48 + j]        = v;
            else        outI[pix*48 + (j - 48)] = v;
        }
    }
}

// K1: W-basis MLP.  grid 4608 = (b*192+h)*3 + wq.
__global__ __launch_bounds__(256) void k1_mlp_w(
    const float* __restrict__ x, const float* __restrict__ W0full,
    const float* __restrict__ b0, const float* __restrict__ g0, const float* __restrict__ be0,
    const float* __restrict__ b1, const float* __restrict__ g1, const float* __restrict__ be1,
    const float* __restrict__ b2,
    const uint4* __restrict__ wsw,
    float* __restrict__ wb_r, float* __restrict__ wb_i)
{
    __shared__ unsigned short aHi[64*72];
    __shared__ unsigned short aLo[64*72];
    int tid = threadIdx.x;
    int wv = __builtin_amdgcn_readfirstlane(tid >> 6);
    int lane = tid & 63, li = lane & 15, quad = lane >> 4;
    int wq = blockIdx.x % 3;
    int bh = blockIdx.x / 3;
    int b = bh / 192, h = bh % 192;
    int w0 = wq * 64;
    int r = wv*16 + li;
    #pragma unroll
    for (int cc = 0; cc < 16; ++cc) {
        int c = cc*4 + quad;
        float v = x[((b*64 + c)*192 + h)*192 + (w0 + r)];
        unsigned short hv = f2bf(v);
        aHi[r*72 + c] = hv;
        aLo[r*72 + c] = f2bf(v - bf2f(hv));
    }
    mlp_body(aHi, aLo, wsw, W0full + 64*64, b0, g0, be0, b1, g1, be1, b2,
             (float)w0, wb_r, wb_i, bh*192 + w0);
}

// K3: H-basis MLP.  grid 1152 = (b*48+m)*3 + hq.  t layout (B,H,C,M2).
__global__ __launch_bounds__(256) void k3_mlp_h(
    const float* __restrict__ t_r, const float* __restrict__ W0full,
    const float* __restrict__ b0, const float* __restrict__ g0, const float* __restrict__ be0,
    const float* __restrict__ b1, const float* __restrict__ g1, const float* __restrict__ be1,
    const float* __restrict__ b2,
    const uint4* __restrict__ wsw,
    float* __restrict__ hb_r, float* __restrict__ hb_i)
{
    __shared__ unsigned short aHi[64*72];
    __shared__ unsigned short aLo[64*72];
    int tid = threadIdx.x;
    int wv = __builtin_amdgcn_readfirstlane(tid >> 6);
    int lane = tid & 63, li = lane & 15, quad = lane >> 4;
    int hq = blockIdx.x % 3;
    int bm = blockIdx.x / 3;
    int b = bm / 48, m = bm % 48;
    int h0 = hq * 64;
    int r = wv*16 + li;
    #pragma unroll
    for (int cc = 0; cc < 16; ++cc) {
        int c = cc*4 + quad;
        float v = t_r[((b*192 + h0 + r)*64 + c)*48 + m];
        unsigned short hv = f2bf(v);
        aHi[r*72 + c] = hv;
        aLo[r*72 + c] = f2bf(v - bf2f(hv));
    }
    mlp_body(aHi, aLo, wsw, W0full + 64*64, b0, g0, be0, b1, g1, be1, b2,
             (float)h0, hb_r, hb_i, bm*192 + h0);
}

// K2: t[b,c,h,m] = sum_w x[b,c,h,w]*wb[b,h,w,m].  grid 1536 = b*192+h.
// t stored (B,H,C,M2) -> fully coalesced stores.
__global__ __launch_bounds__(256) void k2_t(
    const float* __restrict__ x,
    const float* __restrict__ wb_r, const float* __restrict__ wb_i,
    float* __restrict__ t_r, float* __restrict__ t_i)
{
    __shared__ float xs[64*33];
    __shared__ float wbs[32*96];
    int bh = blockIdx.x;                  // b*192 + h
    int b = bh / 192, h = bh % 192;
    int tid = threadIdx.x;
    int c = tid >> 2, mg = tid & 3;
    float accr[12], acci[12];
    #pragma unroll
    for (int k = 0; k < 12; ++k) { accr[k] = 0.f; acci[k] = 0.f; }
    for (int w0 = 0; w0 < 192; w0 += 32) {
        for (int idx = tid; idx < 2048; idx += 256) {
            int cc = idx >> 5, ww = idx & 31;
            xs[cc*33 + ww] = x[((b*64 + cc)*192 + h)*192 + (w0 + ww)];
        }
        for (int idx = tid; idx < 1536; idx += 256) {
            int ww = idx / 48, mm = idx % 48;
            int g = (bh*192 + (w0 + ww))*48 + mm;
            wbs[ww*96 + mm]      = wb_r[g];
            wbs[ww*96 + 48 + mm] = wb_i[g];
        }
        __syncthreads();
        for (int ww = 0; ww < 32; ++ww) {
            float xv = xs[c*33 + ww];
            const float4* wr4 = (const float4*)(wbs + ww*96 + mg*12);
            const float4* wi4 = (const float4*)(wbs + ww*96 + 48 + mg*12);
            #pragma unroll
            for (int q = 0; q < 3; ++q) {
                float4 wr = wr4[q], wi = wi4[q];
                accr[4*q+0] = fmaf(xv, wr.x, accr[4*q+0]);
                accr[4*q+1] = fmaf(xv, wr.y, accr[4*q+1]);
                accr[4*q+2] = fmaf(xv, wr.z, accr[4*q+2]);
                accr[4*q+3] = fmaf(xv, wr.w, accr[4*q+3]);
                acci[4*q+0] = fmaf(xv, wi.x, acci[4*q+0]);
                acci[4*q+1] = fmaf(xv, wi.y, acci[4*q+1]);
                acci[4*q+2] = fmaf(xv, wi.z, acci[4*q+2]);
                acci[4*q+3] = fmaf(xv, wi.w, acci[4*q+3]);
            }
        }
        __syncthreads();
    }
    float* dr = t_r + ((bh)*64 + c)*48 + mg*12;
    float* di = t_i + ((bh)*64 + c)*48 + mg*12;
    #pragma unroll
    for (int q = 0; q < 3; ++q) {
        ((float4*)dr)[q] = make_float4(accr[4*q], accr[4*q+1], accr[4*q+2], accr[4*q+3]);
        ((float4*)di)[q] = make_float4(acci[4*q], acci[4*q+1], acci[4*q+2], acci[4*q+3]);
    }
}

// K4: t2 contraction.  grid 384 = b*48+m.  Writes staging (B,M2,C,N).
__global__ __launch_bounds__(256) void k4_t2(
    const float* __restrict__ t_r, const float* __restrict__ t_i,
    const float* __restrict__ hb_r, const float* __restrict__ hb_i,
    float* __restrict__ t2t_r, float* __restrict__ t2t_i)
{
    __shared__ float tsr[64*33], tsi[64*33];
    __shared__ float hbs[32*96];
    int bm = blockIdx.x;                  // b*48 + m
    int b = bm / 48, m = bm % 48;
    int tid = threadIdx.x;
    int c = tid >> 2, ng = tid & 3;
    float ar[12], ai[12];
    #pragma unroll
    for (int k = 0; k < 12; ++k) { ar[k] = 0.f; ai[k] = 0.f; }
    for (int h0 = 0; h0 < 192; h0 += 32) {
        for (int idx = tid; idx < 2048; idx += 256) {
            int cc = idx >> 5, hh = idx & 31;
            int g = ((b*192 + h0 + hh)*64 + cc)*48 + m;
            tsr[cc*33 + hh] = t_r[g];
            tsi[cc*33 + hh] = t_i[g];
        }
        for (int idx = tid; idx < 1536; idx += 256) {
            int hh = idx / 48, nn = idx % 48;
            int g = (bm*192 + (h0 + hh))*48 + nn;
            hbs[hh*96 + nn]      = hb_r[g];
            hbs[hh*96 + 48 + nn] = hb_i[g];
        }
        __syncthreads();
        for (int hh = 0; hh < 32; ++hh) {
            float tr = tsr[c*33 + hh];
            float ti = tsi[c*33 + hh];
            const float4* hr4 = (const float4*)(hbs + hh*96 + ng*12);
            const float4* hi4 = (const float4*)(hbs + hh*96 + 48 + ng*12);
            #pragma unroll
            for (int q = 0; q < 3; ++q) {
                float4 hr = hr4[q], hi = hi4[q];
                ar[4*q+0] = fmaf(tr, hr.x, fmaf(-ti, hi.x, ar[4*q+0]));
                ai[4*q+0] = fmaf(tr, hi.x, fmaf( ti, hr.x, ai[4*q+0]));
                ar[4*q+1] = fmaf(tr, hr.y, fmaf(-ti, hi.y, ar[4*q+1]));
                ai[4*q+1] = fmaf(tr, hi.y, fmaf( ti, hr.y, ai[4*q+1]));
                ar[4*q+2] = fmaf(tr, hr.z, fmaf(-ti, hi.z, ar[4*q+2]));
                ai[4*q+2] = fmaf(tr, hi.z, fmaf( ti, hr.z, ai[4*q+2]));
                ar[4*q+3] = fmaf(tr, hr.w, fmaf(-ti, hi.w, ar[4*q+3]));
                ai[4*q+3] = fmaf(tr, hi.w, fmaf( ti, hr.w, ai[4*q+3]));
            }
        }
        __syncthreads();
    }
    float* dr = t2t_r + (bm*64 + c)*48 + ng*12;
    float* di = t2t_i + (bm*64 + c)*48 + ng*12;
    #pragma unroll
    for (int q = 0; q < 3; ++q) {
        ((float4*)dr)[q] = make_float4(ar[4*q], ar[4*q+1], ar[4*q+2], ar[4*q+3]);
        ((float4*)di)[q] = make_float4(ai[4*q], ai[4*q+1], ai[4*q+2], ai[4*q+3]);
    }
}

// K4b: transpose t2 staging (B,M2,C,N) -> (B,C,N,M2).  grid 512 = b*64+c.
__global__ __launch_bounds__(256) void k4b_tr(
    const float* __restrict__ sR, const float* __restrict__ sI,
    float* __restrict__ dR, float* __restrict__ dI)
{
    __shared__ float lr[48*49], li_[48*49];
    int bc = blockIdx.x;
    int b = bc >> 6, c = bc & 63;
    int tid = threadIdx.x;
    for (int idx = tid; idx < 2304; idx += 256) {
        int m = idx / 48, n = idx % 48;
        int g = ((b*48 + m)*64 + c)*48 + n;
        lr[m*49 + n]  = sR[g];
        li_[m*49 + n] = sI[g];
    }
    __syncthreads();
    for (int idx = tid; idx < 2304; idx += 256) {
        int n = idx / 48, m = idx % 48;
        int g = ((b*64 + c)*48 + n)*48 + m;
        dR[g] = lr[m*49 + n];
        dI[g] = li_[m*49 + n];
    }
}

// K5: proc[b,o,nm] = sum_i t2[b,i,nm]*Wf[o,i,nm].  grid 288.
__global__ __launch_bounds__(256) void k5_proc(
    const float* __restrict__ t2_r, const float* __restrict__ t2_i,
    const float* __restrict__ fr, const float* __restrict__ fi,
    float* __restrict__ proc_r, float* __restrict__ proc_i)
{
    int og = blockIdx.x & 31;
    int ch = blockIdx.x >> 5;
    int nm = ch*256 + threadIdx.x;
    int o0 = og*2;
    float p0r[8], p0i[8], p1r[8], p1i[8];
    #pragma unroll
    for (int bb = 0; bb < 8; ++bb) { p0r[bb]=0.f; p0i[bb]=0.f; p1r[bb]=0.f; p1i[bb]=0.f; }
    for (int i = 0; i < 64; ++i) {
        float w0r = fr[(o0*64 + i)*2304 + nm];
        float w0i = fi[(o0*64 + i)*2304 + nm];
        float w1r = fr[((o0+1)*64 + i)*2304 + nm];
        float w1i = fi[((o0+1)*64 + i)*2304 + nm];
        #pragma unroll
        for (int bb = 0; bb < 8; ++bb) {
            float tr = t2_r[(bb*64 + i)*2304 + nm];
            float ti = t2_i[(bb*64 + i)*2304 + nm];
            p0r[bb] = fmaf(tr, w0r, fmaf(-ti, w0i, p0r[bb]));
            p0i[bb] = fmaf(tr, w0i, fmaf( ti, w0r, p0i[bb]));
            p1r[bb] = fmaf(tr, w1r, fmaf(-ti, w1i, p1r[bb]));
            p1i[bb] = fmaf(tr, w1i, fmaf( ti, w1r, p1i[bb]));
        }
    }
    #pragma unroll
    for (int bb = 0; bb < 8; ++bb) {
        proc_r[(bb*64 + o0)*2304 + nm]     = p0r[bb];
        proc_i[(bb*64 + o0)*2304 + nm]     = p0i[bb];
        proc_r[(bb*64 + o0 + 1)*2304 + nm] = p1r[bb];
        proc_i[(bb*64 + o0 + 1)*2304 + nm] = p1i[bb];
    }
}

// K6: rec_h[b,o,h,m] = sum_n proc[b,o,n,m]*conj(hb)[b,m,h,n].
// grid 1536 = (b*48+m)*4 + hq.  rec_h stored (B,M2,H,O).
__global__ __launch_bounds__(256) void k6_rech(
    const float* __restrict__ proc_r, const float* __restrict__ proc_i,
    const float* __restrict__ hb_r, const float* __restrict__ hb_i,
    float* __restrict__ rh_r, float* __restrict__ rh_i)
{
    __shared__ float psr[64*49], psi[64*49];
    __shared__ float hsr[48*52], hsi[48*52];
    int hq = blockIdx.x & 3;
    int bm = blockIdx.x >> 2;             // b*48 + m
    int b = bm / 48, m = bm % 48;
    int tid = threadIdx.x;
    int o = tid & 63, hg = tid >> 6;
    for (int idx = tid; idx < 3072; idx += 256) {
        int oo = idx / 48, nn = idx % 48;
        int g = (b*64 + oo)*2304 + nn*48 + m;
        psr[oo*49 + nn] = proc_r[g];
        psi[oo*49 + nn] = proc_i[g];
    }
    for (int idx = tid; idx < 2304; idx += 256) {
        int hh = idx / 48, nn = idx % 48;
        int g = (bm*192 + hq*48 + hh)*48 + nn;
        hsr[hh*52 + nn] = hb_r[g];
        hsi[hh*52 + nn] = hb_i[g];
    }
    __syncthreads();
    float accr[12], acci[12];
    #pragma unroll
    for (int j = 0; j < 12; ++j) { accr[j]=0.f; acci[j]=0.f; }
    for (int n4 = 0; n4 < 48; n4 += 4) {
        float prv[4], piv[4];
        #pragma unroll
        for (int q = 0; q < 4; ++q) {
            prv[q] = psr[o*49 + n4 + q];
            piv[q] = psi[o*49 + n4 + q];
        }
        #pragma unroll
        for (int j = 0; j < 12; ++j) {
            const float4 hr = *(const float4*)(hsr + (hg*12 + j)*52 + n4);
            const float4 hi = *(const float4*)(hsi + (hg*12 + j)*52 + n4);
            accr[j] += prv[0]*hr.x + piv[0]*hi.x
                     + prv[1]*hr.y + piv[1]*hi.y
                     + prv[2]*hr.z + piv[2]*hi.z
                     + prv[3]*hr.w + piv[3]*hi.w;
            acci[j] += piv[0]*hr.x - prv[0]*hi.x
                     + piv[1]*hr.y - prv[1]*hi.y
                     + piv[2]*hr.z - prv[2]*hi.z
                     + piv[3]*hr.w - prv[3]*hi.w;
        }
    }
    #pragma unroll
    for (int j = 0; j < 12; ++j) {
        int h = hq*48 + hg*12 + j;
        int a = (bm*192 + h)*64 + o;
        rh_r[a] = accr[j];
        rh_i[a] = acci[j];
    }
}

// ===========================================================================
// K7 (MFMA): y[pix][o] = (1/HW) * sum_{k=0..95} A[pix][k]*B[k][o],
// A = [wbr | wbi] (K-concat, exact K=96), B = [rhr ; rhi].
// grid 4608 = (b*192+h)*3 + wq; 4 waves x 16 pixel rows.
// ===========================================================================
__global__ __launch_bounds__(256) void k7_rec(
    const float* __restrict__ rh_r, const float* __restrict__ rh_i,
    const float* __restrict__ wb_r, const float* __restrict__ wb_i,
    float* __restrict__ y)
{
    __shared__ unsigned short aHi[64*104];   // 64 rows x K=96 (+8 pad)
    __shared__ unsigned short aLo[64*104];
    __shared__ uint4 bfrag[1536];            // 12 tiles x [hi:64|lo@+768]
    float* cbuf = (float*)bfrag;             // alias, used after barrier

    int wq = blockIdx.x % 3;
    int bh = blockIdx.x / 3;
    int b = bh / 192, h = bh % 192;
    int w0 = wq * 64;
    int tid = threadIdx.x;
    int wv = __builtin_amdgcn_readfirstlane(tid >> 6);
    int lane = tid & 63, li = lane & 15, quad = lane >> 4;
    int rbase = wv*16;
    int row = rbase + li;

    // A staging: wb tile (64 pix x 48 m, r then i) -> hi/lo bf16
    {
        int pix = bh*192 + w0 + row;
        const float4* pr = (const float4*)(wb_r + pix*48) + quad*3;
        const float4* pi = (const float4*)(wb_i + pix*48) + quad*3;
        #pragma unroll
        for (int q = 0; q < 3; ++q) {
            float4 vr = pr[q];
            float4 vi = pi[q];
            int k0 = quad*12 + q*4;
            float vs[8] = {vr.x, vr.y, vr.z, vr.w, vi.x, vi.y, vi.z, vi.w};
            #pragma unroll
            for (int e = 0; e < 4; ++e) {
                unsigned short h1 = f2bf(vs[e]);
                aHi[row*104 + k0 + e] = h1;
                aLo[row*104 + k0 + e] = f2bf(vs[e] - bf2f(h1));
                unsigned short h2 = f2bf(vs[4+e]);
                aHi[row*104 + 48 + k0 + e] = h2;
                aLo[row*104 + 48 + k0 + e] = f2bf(vs[4+e] - bf2f(h2));
            }
        }
    }
    // B-fragment build: 12 tiles (t = nt*3 + ks), each rh element read once
    for (int t = tid >> 6; t < 12; t += 4) {
        int ks = t % 3;
        int nt = t / 3;
        int o = nt*16 + li;
        unsigned hi8[8], lo8[8];
        #pragma unroll
        for (int j = 0; j < 8; ++j) {
            int kk = ks*32 + quad*8 + j;
            const float* src = (kk < 48) ? rh_r : rh_i;
            int m = (kk < 48) ? kk : kk - 48;
            float v = src[((b*48 + m)*192 + h)*64 + o];
            unsigned short hv = f2bf(v);
            hi8[j] = hv;
            lo8[j] = f2bf(v - bf2f(hv));
        }
        uint4 ph, pl;
        ph.x = hi8[0] | (hi8[1]<<16); ph.y = hi8[2] | (hi8[3]<<16);
        ph.z = hi8[4] | (hi8[5]<<16); ph.w = hi8[6] | (hi8[7]<<16);
        pl.x = lo8[0] | (lo8[1]<<16); pl.y = lo8[2] | (lo8[3]<<16);
        pl.z = lo8[4] | (lo8[5]<<16); pl.w = lo8[6] | (lo8[7]<<16);
        bfrag[t*64 + lane]       = ph;
        bfrag[768 + t*64 + lane] = pl;
    }
    __syncthreads();

    union U { uint4 u; bf16x8 b; };
    bf16x8 aH[3], aL[3];
    #pragma unroll
    for (int ks = 0; ks < 3; ++ks) {
        aH[ks] = *(const bf16x8*)&aHi[row*104 + ks*32 + quad*8];
        aL[ks] = *(const bf16x8*)&aLo[row*104 + ks*32 + quad*8];
    }
    f32x4 acc[4];
    #pragma unroll
    for (int nt = 0; nt < 4; ++nt) {
        f32x4 a = {0.f, 0.f, 0.f, 0.f};
        #pragma unroll
        for (int ks = 0; ks < 3; ++ks) {
            int t = nt*3 + ks;
            U bh_, bl_;
            bh_.u = bfrag[t*64 + lane];
            bl_.u = bfrag[768 + t*64 + lane];
            a = __builtin_amdgcn_mfma_f32_16x16x32_bf16(aH[ks], bh_.b, a, 0, 0, 0);
            a = __builtin_amdgcn_mfma_f32_16x16x32_bf16(aH[ks], bl_.b, a, 0, 0, 0);
            a = __builtin_amdgcn_mfma_f32_16x16x32_bf16(aL[ks], bh_.b, a, 0, 0, 0);
        }
        acc[nt] = a;
    }
    __syncthreads();                       // all bfrag reads done; cbuf aliases it
    const float s = 1.0f / 36864.0f;
    #pragma unroll
    for (int nt = 0; nt < 4; ++nt) {
        int o = nt*16 + li;
        #pragma unroll
        for (int rg = 0; rg < 4; ++rg) {
            int prow = rbase + quad*4 + rg;
            cbuf[prow*67 + o] = acc[nt][rg] * s;
        }
    }
    __syncthreads();
    #pragma unroll
    for (int it = 0; it < 16; ++it) {
        int o = it*4 + (tid >> 6);
        int pix = tid & 63;
        y[((b*64 + o)*192 + h)*192 + w0 + pix] = cbuf[pix*67 + o];
    }
}

// ===========================================================================
// K8 (VALU rewrite): mixer GEMM + channel-LN + GELU + shortcut GEMM + GELU.
// One pixel per (lane, wave-pair); o split 32/32 across wave pairs so the
// weight stream is wave-uniform (scalar s_load through K$).  No MFMA, no
// bf16 split, no LDS staging -> fp32-exact GEMM, coalesced per-c loads.
// grid 2304 = 294912 pixels / 128 pixels per block.
// ===========================================================================
__global__ __launch_bounds__(256) void k8_final(
    const float* __restrict__ y, const float* __restrict__ x,
    const float* __restrict__ mw, const float* __restrict__ sw,
    const float* __restrict__ mb,
    const float* __restrict__ nrm_g, const float* __restrict__ nrm_b,
    const float* __restrict__ sb,
    float* __restrict__ out)
{
    __shared__ float2 red[4][64];          // LN partial sums per wave
    int tid  = threadIdx.x;
    int lane = tid & 63;
    int wv   = __builtin_amdgcn_readfirstlane(tid >> 6);
    int og   = wv & 1;                     // which 32 output channels
    int half = wv >> 1;                    // which 64-pixel half
    int o0   = og * 32;
    int b    = blockIdx.x / 288;           // 288 blocks per batch (36864/128)
    int hw   = (blockIdx.x % 288) * 128 + half*64 + lane;
    const float* ybase = y + (b*64)*36864 + hw;
    const float* xbase = x + (b*64)*36864 + hw;

    // ---- mixer GEMM: v[j] = mb[o0+j] + sum_c mw[(o0+j)*64+c] * y[c][pix]
    float v[32];
    #pragma unroll
    for (int j = 0; j < 32; ++j) v[j] = mb[o0 + j];
    #pragma unroll 4
    for (int c4 = 0; c4 < 16; ++c4) {
        float y0 = ybase[(c4*4 + 0)*36864];
        float y1 = ybase[(c4*4 + 1)*36864];
        float y2 = ybase[(c4*4 + 2)*36864];
        float y3 = ybase[(c4*4 + 3)*36864];
        #pragma unroll
        for (int j = 0; j < 32; ++j) {
            const float* wr = mw + (o0 + j)*64 + c4*4;
            float a = v[j];
            a = fmaf(wr[0], y0, a);
            a = fmaf(wr[1], y1, a);
            a = fmaf(wr[2], y2, a);
            a = fmaf(wr[3], y3, a);
            v[j] = a;
        }
    }

    // ---- channel LN (over all 64 o): combine the two og-wave partials
    float s1 = 0.f, s2 = 0.f;
    #pragma unroll
    for (int j = 0; j < 32; ++j) { s1 += v[j]; s2 = fmaf(v[j], v[j], s2); }
    red[wv][lane] = make_float2(s1, s2);
    __syncthreads();
    float2 other = red[wv ^ 1][lane];
    s1 += other.x; s2 += other.y;
    float mu   = s1 * 0.015625f;
    float rstd = rsqrtf(s2 * 0.015625f - mu*mu + LN_EPS);
    #pragma unroll
    for (int j = 0; j < 32; ++j)
        v[j] = gelu_f(fmaf((v[j] - mu) * rstd, nrm_g[o0 + j], nrm_b[o0 + j]));

    // ---- shortcut GEMM: sc[j] = sb[o0+j] + sum_c sw[(o0+j)*64+c] * x[c][pix]
    float sc[32];
    #pragma unroll
    for (int j = 0; j < 32; ++j) sc[j] = sb[o0 + j];
    #pragma unroll 4
    for (int c4 = 0; c4 < 16; ++c4) {
        float x0 = xbase[(c4*4 + 0)*36864];
        float x1 = xbase[(c4*4 + 1)*36864];
        float x2 = xbase[(c4*4 + 2)*36864];
        float x3 = xbase[(c4*4 + 3)*36864];
        #pragma unroll
        for (int j = 0; j < 32; ++j) {
            const float* wr = sw + (o0 + j)*64 + c4*4;
            float a = sc[j];
            a = fmaf(wr[0], x0, a);
            a = fmaf(wr[1], x1, a);
            a = fmaf(wr[2], x2, a);
            a = fmaf(wr[3], x3, a);
            sc[j] = a;
        }
    }

    // ---- final gelu + coalesced store (per j: lanes = consecutive hw)
    #pragma unroll
    for (int j = 0; j < 32; ++j)
        out[(b*64 + o0 + j)*36864 + hw] = gelu_f(v[j] + sc[j]);
}

extern "C" void kernel_launch(void* const* d_in, const int* in_sizes, int n_in,
                              void* d_out, int out_size, void* d_ws, size_t ws_size,
                              hipStream_t stream)
{
    (void)in_sizes; (void)n_in; (void)out_size; (void)ws_size;
    const float* x    = (const float*)d_in[0];
    const float* wW0  = (const float*)d_in[1];
    const float* wb0  = (const float*)d_in[2];
    const float* wg0  = (const float*)d_in[3];
    const float* wbe0 = (const float*)d_in[4];
    const float* wW1  = (const float*)d_in[5];
    const float* wb1  = (const float*)d_in[6];
    const float* wg1  = (const float*)d_in[7];
    const float* wbe1 = (const float*)d_in[8];
    const float* wW2  = (const float*)d_in[9];
    const float* wb2  = (const float*)d_in[10];
    const float* hW0  = (const float*)d_in[11];
    const float* hb0  = (const float*)d_in[12];
    const float* hg0  = (const float*)d_in[13];
    const float* hbe0 = (const float*)d_in[14];
    const float* hW1  = (const float*)d_in[15];
    const float* hb1  = (const float*)d_in[16];
    const float* hg1  = (const float*)d_in[17];
    const float* hbe1 = (const float*)d_in[18];
    const float* hW2  = (const float*)d_in[19];
    const float* hb2  = (const float*)d_in[20];
    const float* fr   = (const float*)d_in[21];
    const float* fi   = (const float*)d_in[22];
    const float* mw   = (const float*)d_in[23];
    const float* mb   = (const float*)d_in[24];
    const float* ngp  = (const float*)d_in[25];
    const float* nbp  = (const float*)d_in[26];
    const float* sw   = (const float*)d_in[27];
    const float* sb   = (const float*)d_in[28];
    float* out = (float*)d_out;

    float* ws   = (float*)d_ws;
    float* wbr  = ws;                  // 14,155,776  (B,H,W,M2)
    float* wbi  = ws + 14155776;
    float* t_r  = ws + 28311552;       //  4,718,592  (B,H,C,M2)
    float* t_i  = ws + 33030144;
    float* hbr  = ws + 37748736;       //  3,538,944  (B,M2,H,M1)
    float* hbi  = ws + 41287680;
    float* t2r  = ws + 44826624;       //  1,179,648  (B,C,M1,M2)
    float* t2i  = ws + 46006272;
    float* prr  = ws + 47185920;       //  staging (B,M2,C,N) then proc (B,O,M1,M2)
    float* pri  = ws + 48365568;
    float* rhr  = t_r;                 // reuse: t dead after k4b -> rec_h (B,M2,H,O)
    float* rhi  = t_i;
    float* yb   = ws + 49545216;       // 18,874,368  (B,O,H,W)
    uint4* wsw  = (uint4*)yb;          // MLP weights (dead until k7 writes y)

    k0_swizzle<<<dim3(6), dim3(256), 0, stream>>>(wW0, wW1, wW2, hW0, hW1, hW2, wsw);
    k1_mlp_w<<<dim3(4608), dim3(256), 0, stream>>>(x, wW0, wb0, wg0, wbe0,
                                                   wb1, wg1, wbe1, wb2, wsw, wbr, wbi);
    k2_t<<<dim3(1536), dim3(256), 0, stream>>>(x, wbr, wbi, t_r, t_i);
    k3_mlp_h<<<dim3(1152), dim3(256), 0, stream>>>(t_r, hW0, hb0, hg0, hbe0,
                                                   hb1, hg1, hbe1, hb2, wsw + 3584, hbr, hbi);
    k4_t2<<<dim3(384), dim3(256), 0, stream>>>(t_r, t_i, hbr, hbi, prr, pri);
    k4b_tr<<<dim3(512), dim3(256), 0, stream>>>(prr, pri, t2r, t2i);
    k5_proc<<<dim3(288), dim3(256), 0, stream>>>(t2r, t2i, fr, fi, prr, pri);
    k6_rech<<<dim3(1536), dim3(256), 0, stream>>>(prr, pri, hbr, hbi, rhr, rhi);
    k7_rec<<<dim3(4608), dim3(256), 0, stream>>>(rhr, rhi, wbr, wbi, yb);
    k8_final<<<dim3(2304), dim3(256), 0, stream>>>(yb, x, mw, sw, mb, ngp, nbp, sb, out);
}

// Round 2
// 725.553 us; speedup vs baseline: 1.5799x; 1.5799x over previous
//
#include <hip/hip_runtime.h>
#include <math.h>

#define LN_EPS 1e-5f

typedef short bf16x8 __attribute__((ext_vector_type(8)));
typedef float f32x4  __attribute__((ext_vector_type(4)));

__device__ __forceinline__ float gelu_f(float v) {
    return 0.5f * v * (1.0f + erff(v * 0.70710678118654752f));
}
__device__ __forceinline__ unsigned short f2bf(float f) {
    unsigned u = __float_as_uint(f);
    return (unsigned short)((u + 0x7fffu + ((u >> 16) & 1u)) >> 16);
}
__device__ __forceinline__ float bf2f(unsigned short h) {
    return __uint_as_float(((unsigned)h) << 16);
}

// ===========================================================================
// K0: swizzle MLP weights into MFMA B-fragment order, split hi/lo bf16.
// B[k][n], n = lane&15, k = (lane>>4)*8 + j.  Per tile: 128 uint4 = [hi|lo].
// ===========================================================================
__global__ __launch_bounds__(256) void k0_swizzle(
    const float* __restrict__ wW0, const float* __restrict__ wW1, const float* __restrict__ wW2,
    const float* __restrict__ hW0, const float* __restrict__ hW1, const float* __restrict__ hW2,
    uint4* __restrict__ dst)
{
    int mat = blockIdx.x;
    const float* W; int N, ntiles, base;
    switch (mat) {
      case 0: W=wW0; N=64; ntiles=8;  base=0;    break;
      case 1: W=wW1; N=64; ntiles=8;  base=1024; break;
      case 2: W=wW2; N=96; ntiles=12; base=2048; break;
      case 3: W=hW0; N=64; ntiles=8;  base=3584; break;
      case 4: W=hW1; N=64; ntiles=8;  base=4608; break;
      default:W=hW2; N=96; ntiles=12; base=5632; break;
    }
    int lane = threadIdx.x & 63;
    for (int t = threadIdx.x >> 6; t < ntiles; t += 4) {
        int nt = t >> 1, ks = t & 1;
        int n  = nt*16 + (lane & 15);
        int k0 = ks*32 + (lane >> 4)*8;
        unsigned hi[8], lo[8];
        #pragma unroll
        for (int j = 0; j < 8; ++j) {
            float v = W[(k0 + j)*N + n];
            unsigned short h = f2bf(v);
            hi[j] = h;
            lo[j] = f2bf(v - bf2f(h));
        }
        uint4 ph, pl;
        ph.x = hi[0] | (hi[1]<<16); ph.y = hi[2] | (hi[3]<<16);
        ph.z = hi[4] | (hi[5]<<16); ph.w = hi[6] | (hi[7]<<16);
        pl.x = lo[0] | (lo[1]<<16); pl.y = lo[2] | (lo[3]<<16);
        pl.z = lo[4] | (lo[5]<<16); pl.w = lo[6] | (lo[7]<<16);
        dst[base + t*128 + lane]      = ph;
        dst[base + t*128 + 64 + lane] = pl;
    }
}

// K0b: swizzle mixer/shortcut weights (transposed: B[k=c][n=o] = W[o*64+c]).
__global__ __launch_bounds__(256) void k0b_swizzle(
    const float* __restrict__ mw, const float* __restrict__ sw,
    uint4* __restrict__ dst)
{
    int mat = blockIdx.x;
    const float* W = mat ? sw : mw;
    int base = mat ? 1024 : 0;
    int lane = threadIdx.x & 63;
    for (int t = threadIdx.x >> 6; t < 8; t += 4) {
        int nt = t >> 1, ks = t & 1;
        int n  = nt*16 + (lane & 15);
        int k0 = ks*32 + (lane >> 4)*8;
        unsigned hi[8], lo[8];
        #pragma unroll
        for (int j = 0; j < 8; ++j) {
            float v = W[n*64 + (k0 + j)];
            unsigned short h = f2bf(v);
            hi[j] = h;
            lo[j] = f2bf(v - bf2f(h));
        }
        uint4 ph, pl;
        ph.x = hi[0] | (hi[1]<<16); ph.y = hi[2] | (hi[3]<<16);
        ph.z = hi[4] | (hi[5]<<16); ph.w = hi[6] | (hi[7]<<16);
        pl.x = lo[0] | (lo[1]<<16); pl.y = lo[2] | (lo[3]<<16);
        pl.z = lo[4] | (lo[5]<<16); pl.w = lo[6] | (lo[7]<<16);
        dst[base + t*128 + lane]      = ph;
        dst[base + t*128 + 64 + lane] = pl;
    }
}

// ===========================================================================
// Split-precision MFMA GEMM helper (wave-private 16 rows in LDS).
// ===========================================================================
template<int NT, int STRIDE>
__device__ __forceinline__ void gemm64s(
    const unsigned short* aHi, const unsigned short* aLo,
    const uint4* __restrict__ wsw, int tbase, int row, int quad, int lane,
    f32x4* acc)
{
    union U { uint4 u; bf16x8 b; };
    bf16x8 aH[2], aL[2];
    #pragma unroll
    for (int ks = 0; ks < 2; ++ks) {
        aH[ks] = *(const bf16x8*)&aHi[row*STRIDE + ks*32 + quad*8];
        aL[ks] = *(const bf16x8*)&aLo[row*STRIDE + ks*32 + quad*8];
    }
    #pragma unroll
    for (int nt = 0; nt < NT; ++nt) {
        f32x4 a = {0.f, 0.f, 0.f, 0.f};
        #pragma unroll
        for (int ks = 0; ks < 2; ++ks) {
            int t = tbase + nt*2 + ks;
            U bh, bl;
            bh.u = wsw[t*128 + lane];
            bl.u = wsw[t*128 + 64 + lane];
            a = __builtin_amdgcn_mfma_f32_16x16x32_bf16(aH[ks], bh.b, a, 0, 0, 0);
            a = __builtin_amdgcn_mfma_f32_16x16x32_bf16(aH[ks], bl.b, a, 0, 0, 0);
            a = __builtin_amdgcn_mfma_f32_16x16x32_bf16(aL[ks], bh.b, a, 0, 0, 0);
        }
        acc[nt] = a;
    }
}

template<int NT>
__device__ __forceinline__ void gemm64(
    const unsigned short* aHi, const unsigned short* aLo,
    const uint4* __restrict__ wsw, int tbase, int row, int quad, int lane,
    f32x4* acc)
{
    gemm64s<NT, 72>(aHi, aLo, wsw, tbase, row, quad, lane, acc);
}

__device__ __forceinline__ void ln_gelu_pass(
    f32x4* acc, const float* __restrict__ bias, const float* __restrict__ wrow,
    float coordBase, float coordScale,
    const float* __restrict__ gg, const float* __restrict__ bb,
    unsigned short* aHi, unsigned short* aLo, int rbase, int quad, int li)
{
    float vals[4][4];
    float s1[4] = {0,0,0,0}, s2[4] = {0,0,0,0};
    #pragma unroll
    for (int nt = 0; nt < 4; ++nt) {
        int col = nt*16 + li;
        float bv = bias[col];
        float br = wrow[col];
        #pragma unroll
        for (int rg = 0; rg < 4; ++rg) {
            float coord = (coordBase + (float)(rbase + quad*4 + rg)) * coordScale;
            float v = acc[nt][rg] + fmaf(coord, br, bv);
            vals[nt][rg] = v;
            s1[rg] += v;
            s2[rg] = fmaf(v, v, s2[rg]);
        }
    }
    #pragma unroll
    for (int d = 1; d < 16; d <<= 1) {
        #pragma unroll
        for (int rg = 0; rg < 4; ++rg) {
            s1[rg] += __shfl_xor(s1[rg], d, 64);
            s2[rg] += __shfl_xor(s2[rg], d, 64);
        }
    }
    #pragma unroll
    for (int nt = 0; nt < 4; ++nt) {
        int col = nt*16 + li;
        float gv = gg[col], bev = bb[col];
        #pragma unroll
        for (int rg = 0; rg < 4; ++rg) {
            float mu   = s1[rg] * 0.015625f;
            float rstd = rsqrtf(s2[rg]*0.015625f - mu*mu + LN_EPS);
            float v = gelu_f(fmaf((vals[nt][rg] - mu)*rstd, gv, bev));
            int r = rbase + quad*4 + rg;
            unsigned short hv = f2bf(v);
            aHi[r*72 + col] = hv;
            aLo[r*72 + col] = f2bf(v - bf2f(hv));
        }
    }
}

__device__ __forceinline__ void mlp_body(
    unsigned short* aHi, unsigned short* aLo,
    const uint4* __restrict__ wsw,
    const float* __restrict__ w0row,
    const float* __restrict__ b0, const float* __restrict__ g0, const float* __restrict__ be0,
    const float* __restrict__ b1, const float* __restrict__ g1, const float* __restrict__ be1,
    const float* __restrict__ b2,
    float coordBase,
    float* __restrict__ outR, float* __restrict__ outI, int pixBase)
{
    int tid = threadIdx.x;
    int wv = __builtin_amdgcn_readfirstlane(tid >> 6);
    int lane = tid & 63, li = lane & 15, quad = lane >> 4;
    int rbase = wv*16;
    int row = rbase + li;
    f32x4 acc[6];

    gemm64<4>(aHi, aLo, wsw, 0, row, quad, lane, acc);
    ln_gelu_pass(acc, b0, w0row, coordBase, 1.0f/191.0f, g0, be0, aHi, aLo, rbase, quad, li);
    gemm64<4>(aHi, aLo, wsw, 8, row, quad, lane, acc);
    ln_gelu_pass(acc, b1, b1, 0.f, 0.f, g1, be1, aHi, aLo, rbase, quad, li);
    gemm64<6>(aHi, aLo, wsw, 16, row, quad, lane, acc);
    #pragma unroll
    for (int nt = 0; nt < 6; ++nt) {
        int j = nt*16 + li;
        float bv = b2[j];
        #pragma unroll
        for (int rg = 0; rg < 4; ++rg) {
            float v = acc[nt][rg] + bv;
            int pix = pixBase + rbase + quad*4 + rg;
            if (nt < 3) outR[pix*48 + j]        = v;
            else        outI[pix*48 + (j - 48)] = v;
        }
    }
}

// K1: W-basis MLP.  grid 4608 = (b*192+h)*3 + wq.
__global__ __launch_bounds__(256) void k1_mlp_w(
    const float* __restrict__ x, const float* __restrict__ W0full,
    const float* __restrict__ b0, const float* __restrict__ g0, const float* __restrict__ be0,
    const float* __restrict__ b1, const float* __restrict__ g1, const float* __restrict__ be1,
    const float* __restrict__ b2,
    const uint4* __restrict__ wsw,
    float* __restrict__ wb_r, float* __restrict__ wb_i)
{
    __shared__ unsigned short aHi[64*72];
    __shared__ unsigned short aLo[64*72];
    int tid = threadIdx.x;
    int wv = __builtin_amdgcn_readfirstlane(tid >> 6);
    int lane = tid & 63, li = lane & 15, quad = lane >> 4;
    int wq = blockIdx.x % 3;
    int bh = blockIdx.x / 3;
    int b = bh / 192, h = bh % 192;
    int w0 = wq * 64;
    int r = wv*16 + li;
    #pragma unroll
    for (int cc = 0; cc < 16; ++cc) {
        int c = cc*4 + quad;
        float v = x[((b*64 + c)*192 + h)*192 + (w0 + r)];
        unsigned short hv = f2bf(v);
        aHi[r*72 + c] = hv;
        aLo[r*72 + c] = f2bf(v - bf2f(hv));
    }
    mlp_body(aHi, aLo, wsw, W0full + 64*64, b0, g0, be0, b1, g1, be1, b2,
             (float)w0, wb_r, wb_i, bh*192 + w0);
}

// K3: H-basis MLP.  grid 1152 = (b*48+m)*3 + hq.  t layout (B,H,C,M2).
__global__ __launch_bounds__(256) void k3_mlp_h(
    const float* __restrict__ t_r, const float* __restrict__ W0full,
    const float* __restrict__ b0, const float* __restrict__ g0, const float* __restrict__ be0,
    const float* __restrict__ b1, const float* __restrict__ g1, const float* __restrict__ be1,
    const float* __restrict__ b2,
    const uint4* __restrict__ wsw,
    float* __restrict__ hb_r, float* __restrict__ hb_i)
{
    __shared__ unsigned short aHi[64*72];
    __shared__ unsigned short aLo[64*72];
    int tid = threadIdx.x;
    int wv = __builtin_amdgcn_readfirstlane(tid >> 6);
    int lane = tid & 63, li = lane & 15, quad = lane >> 4;
    int hq = blockIdx.x % 3;
    int bm = blockIdx.x / 3;
    int b = bm / 48, m = bm % 48;
    int h0 = hq * 64;
    int r = wv*16 + li;
    #pragma unroll
    for (int cc = 0; cc < 16; ++cc) {
        int c = cc*4 + quad;
        float v = t_r[((b*192 + h0 + r)*64 + c)*48 + m];
        unsigned short hv = f2bf(v);
        aHi[r*72 + c] = hv;
        aLo[r*72 + c] = f2bf(v - bf2f(hv));
    }
    mlp_body(aHi, aLo, wsw, W0full + 64*64, b0, g0, be0, b1, g1, be1, b2,
             (float)h0, hb_r, hb_i, bm*192 + h0);
}

// K2: t[b,c,h,m] = sum_w x[b,c,h,w]*wb[b,h,w,m].  grid 1536 = b*192+h.
__global__ __launch_bounds__(256) void k2_t(
    const float* __restrict__ x,
    const float* __restrict__ wb_r, const float* __restrict__ wb_i,
    float* __restrict__ t_r, float* __restrict__ t_i)
{
    __shared__ float xs[64*33];
    __shared__ float wbs[32*96];
    int bh = blockIdx.x;                  // b*192 + h
    int b = bh / 192, h = bh % 192;
    int tid = threadIdx.x;
    int c = tid >> 2, mg = tid & 3;
    float accr[12], acci[12];
    #pragma unroll
    for (int k = 0; k < 12; ++k) { accr[k] = 0.f; acci[k] = 0.f; }
    for (int w0 = 0; w0 < 192; w0 += 32) {
        for (int idx = tid; idx < 2048; idx += 256) {
            int cc = idx >> 5, ww = idx & 31;
            xs[cc*33 + ww] = x[((b*64 + cc)*192 + h)*192 + (w0 + ww)];
        }
        for (int idx = tid; idx < 1536; idx += 256) {
            int ww = idx / 48, mm = idx % 48;
            int g = (bh*192 + (w0 + ww))*48 + mm;
            wbs[ww*96 + mm]      = wb_r[g];
            wbs[ww*96 + 48 + mm] = wb_i[g];
        }
        __syncthreads();
        for (int ww = 0; ww < 32; ++ww) {
            float xv = xs[c*33 + ww];
            const float4* wr4 = (const float4*)(wbs + ww*96 + mg*12);
            const float4* wi4 = (const float4*)(wbs + ww*96 + 48 + mg*12);
            #pragma unroll
            for (int q = 0; q < 3; ++q) {
                float4 wr = wr4[q], wi = wi4[q];
                accr[4*q+0] = fmaf(xv, wr.x, accr[4*q+0]);
                accr[4*q+1] = fmaf(xv, wr.y, accr[4*q+1]);
                accr[4*q+2] = fmaf(xv, wr.z, accr[4*q+2]);
                accr[4*q+3] = fmaf(xv, wr.w, accr[4*q+3]);
                acci[4*q+0] = fmaf(xv, wi.x, acci[4*q+0]);
                acci[4*q+1] = fmaf(xv, wi.y, acci[4*q+1]);
                acci[4*q+2] = fmaf(xv, wi.z, acci[4*q+2]);
                acci[4*q+3] = fmaf(xv, wi.w, acci[4*q+3]);
            }
        }
        __syncthreads();
    }
    float* dr = t_r + ((bh)*64 + c)*48 + mg*12;
    float* di = t_i + ((bh)*64 + c)*48 + mg*12;
    #pragma unroll
    for (int q = 0; q < 3; ++q) {
        ((float4*)dr)[q] = make_float4(accr[4*q], accr[4*q+1], accr[4*q+2], accr[4*q+3]);
        ((float4*)di)[q] = make_float4(acci[4*q], acci[4*q+1], acci[4*q+2], acci[4*q+3]);
    }
}

// K4: t2 contraction.  grid 384 = b*48+m.  Writes staging (B,M2,C,N).
__global__ __launch_bounds__(256) void k4_t2(
    const float* __restrict__ t_r, const float* __restrict__ t_i,
    const float* __restrict__ hb_r, const float* __restrict__ hb_i,
    float* __restrict__ t2t_r, float* __restrict__ t2t_i)
{
    __shared__ float tsr[64*33], tsi[64*33];
    __shared__ float hbs[32*96];
    int bm = blockIdx.x;                  // b*48 + m
    int b = bm / 48, m = bm % 48;
    int tid = threadIdx.x;
    int c = tid >> 2, ng = tid & 3;
    float ar[12], ai[12];
    #pragma unroll
    for (int k = 0; k < 12; ++k) { ar[k] = 0.f; ai[k] = 0.f; }
    for (int h0 = 0; h0 < 192; h0 += 32) {
        for (int idx = tid; idx < 2048; idx += 256) {
            int cc = idx >> 5, hh = idx & 31;
            int g = ((b*192 + h0 + hh)*64 + cc)*48 + m;
            tsr[cc*33 + hh] = t_r[g];
            tsi[cc*33 + hh] = t_i[g];
        }
        for (int idx = tid; idx < 1536; idx += 256) {
            int hh = idx / 48, nn = idx % 48;
            int g = (bm*192 + (h0 + hh))*48 + nn;
            hbs[hh*96 + nn]      = hb_r[g];
            hbs[hh*96 + 48 + nn] = hb_i[g];
        }
        __syncthreads();
        for (int hh = 0; hh < 32; ++hh) {
            float tr = tsr[c*33 + hh];
            float ti = tsi[c*33 + hh];
            const float4* hr4 = (const float4*)(hbs + hh*96 + ng*12);
            const float4* hi4 = (const float4*)(hbs + hh*96 + 48 + ng*12);
            #pragma unroll
            for (int q = 0; q < 3; ++q) {
                float4 hr = hr4[q], hi = hi4[q];
                ar[4*q+0] = fmaf(tr, hr.x, fmaf(-ti, hi.x, ar[4*q+0]));
                ai[4*q+0] = fmaf(tr, hi.x, fmaf( ti, hr.x, ai[4*q+0]));
                ar[4*q+1] = fmaf(tr, hr.y, fmaf(-ti, hi.y, ar[4*q+1]));
                ai[4*q+1] = fmaf(tr, hi.y, fmaf( ti, hr.y, ai[4*q+1]));
                ar[4*q+2] = fmaf(tr, hr.z, fmaf(-ti, hi.z, ar[4*q+2]));
                ai[4*q+2] = fmaf(tr, hi.z, fmaf( ti, hr.z, ai[4*q+2]));
                ar[4*q+3] = fmaf(tr, hr.w, fmaf(-ti, hi.w, ar[4*q+3]));
                ai[4*q+3] = fmaf(tr, hi.w, fmaf( ti, hr.w, ai[4*q+3]));
            }
        }
        __syncthreads();
    }
    float* dr = t2t_r + (bm*64 + c)*48 + ng*12;
    float* di = t2t_i + (bm*64 + c)*48 + ng*12;
    #pragma unroll
    for (int q = 0; q < 3; ++q) {
        ((float4*)dr)[q] = make_float4(ar[4*q], ar[4*q+1], ar[4*q+2], ar[4*q+3]);
        ((float4*)di)[q] = make_float4(ai[4*q], ai[4*q+1], ai[4*q+2], ai[4*q+3]);
    }
}

// K4b: transpose t2 staging (B,M2,C,N) -> (B,C,N,M2).  grid 512 = b*64+c.
__global__ __launch_bounds__(256) void k4b_tr(
    const float* __restrict__ sR, const float* __restrict__ sI,
    float* __restrict__ dR, float* __restrict__ dI)
{
    __shared__ float lr[48*49], li_[48*49];
    int bc = blockIdx.x;
    int b = bc >> 6, c = bc & 63;
    int tid = threadIdx.x;
    for (int idx = tid; idx < 2304; idx += 256) {
        int m = idx / 48, n = idx % 48;
        int g = ((b*48 + m)*64 + c)*48 + n;
        lr[m*49 + n]  = sR[g];
        li_[m*49 + n] = sI[g];
    }
    __syncthreads();
    for (int idx = tid; idx < 2304; idx += 256) {
        int n = idx / 48, m = idx % 48;
        int g = ((b*64 + c)*48 + n)*48 + m;
        dR[g] = lr[m*49 + n];
        dI[g] = li_[m*49 + n];
    }
}

// K5: proc[b,o,nm] = sum_i t2[b,i,nm]*Wf[o,i,nm].  grid 288.
__global__ __launch_bounds__(256) void k5_proc(
    const float* __restrict__ t2_r, const float* __restrict__ t2_i,
    const float* __restrict__ fr, const float* __restrict__ fi,
    float* __restrict__ proc_r, float* __restrict__ proc_i)
{
    int og = blockIdx.x & 31;
    int ch = blockIdx.x >> 5;
    int nm = ch*256 + threadIdx.x;
    int o0 = og*2;
    float p0r[8], p0i[8], p1r[8], p1i[8];
    #pragma unroll
    for (int bb = 0; bb < 8; ++bb) { p0r[bb]=0.f; p0i[bb]=0.f; p1r[bb]=0.f; p1i[bb]=0.f; }
    for (int i = 0; i < 64; ++i) {
        float w0r = fr[(o0*64 + i)*2304 + nm];
        float w0i = fi[(o0*64 + i)*2304 + nm];
        float w1r = fr[((o0+1)*64 + i)*2304 + nm];
        float w1i = fi[((o0+1)*64 + i)*2304 + nm];
        #pragma unroll
        for (int bb = 0; bb < 8; ++bb) {
            float tr = t2_r[(bb*64 + i)*2304 + nm];
            float ti = t2_i[(bb*64 + i)*2304 + nm];
            p0r[bb] = fmaf(tr, w0r, fmaf(-ti, w0i, p0r[bb]));
            p0i[bb] = fmaf(tr, w0i, fmaf( ti, w0r, p0i[bb]));
            p1r[bb] = fmaf(tr, w1r, fmaf(-ti, w1i, p1r[bb]));
            p1i[bb] = fmaf(tr, w1i, fmaf( ti, w1r, p1i[bb]));
        }
    }
    #pragma unroll
    for (int bb = 0; bb < 8; ++bb) {
        proc_r[(bb*64 + o0)*2304 + nm]     = p0r[bb];
        proc_i[(bb*64 + o0)*2304 + nm]     = p0i[bb];
        proc_r[(bb*64 + o0 + 1)*2304 + nm] = p1r[bb];
        proc_i[(bb*64 + o0 + 1)*2304 + nm] = p1i[bb];
    }
}

// K6: rec_h[b,o,h,m] = sum_n proc[b,o,n,m]*conj(hb)[b,m,h,n].
// grid 1536 = (b*48+m)*4 + hq.  rec_h stored (B,M2,H,O).
__global__ __launch_bounds__(256) void k6_rech(
    const float* __restrict__ proc_r, const float* __restrict__ proc_i,
    const float* __restrict__ hb_r, const float* __restrict__ hb_i,
    float* __restrict__ rh_r, float* __restrict__ rh_i)
{
    __shared__ float psr[64*49], psi[64*49];
    __shared__ float hsr[48*52], hsi[48*52];
    int hq = blockIdx.x & 3;
    int bm = blockIdx.x >> 2;             // b*48 + m
    int b = bm / 48, m = bm % 48;
    int tid = threadIdx.x;
    int o = tid & 63, hg = tid >> 6;
    for (int idx = tid; idx < 3072; idx += 256) {
        int oo = idx / 48, nn = idx % 48;
        int g = (b*64 + oo)*2304 + nn*48 + m;
        psr[oo*49 + nn] = proc_r[g];
        psi[oo*49 + nn] = proc_i[g];
    }
    for (int idx = tid; idx < 2304; idx += 256) {
        int hh = idx / 48, nn = idx % 48;
        int g = (bm*192 + hq*48 + hh)*48 + nn;
        hsr[hh*52 + nn] = hb_r[g];
        hsi[hh*52 + nn] = hb_i[g];
    }
    __syncthreads();
    float accr[12], acci[12];
    #pragma unroll
    for (int j = 0; j < 12; ++j) { accr[j]=0.f; acci[j]=0.f; }
    for (int n4 = 0; n4 < 48; n4 += 4) {
        float prv[4], piv[4];
        #pragma unroll
        for (int q = 0; q < 4; ++q) {
            prv[q] = psr[o*49 + n4 + q];
            piv[q] = psi[o*49 + n4 + q];
        }
        #pragma unroll
        for (int j = 0; j < 12; ++j) {
            const float4 hr = *(const float4*)(hsr + (hg*12 + j)*52 + n4);
            const float4 hi = *(const float4*)(hsi + (hg*12 + j)*52 + n4);
            accr[j] += prv[0]*hr.x + piv[0]*hi.x
                     + prv[1]*hr.y + piv[1]*hi.y
                     + prv[2]*hr.z + piv[2]*hi.z
                     + prv[3]*hr.w + piv[3]*hi.w;
            acci[j] += piv[0]*hr.x - prv[0]*hi.x
                     + piv[1]*hr.y - prv[1]*hi.y
                     + piv[2]*hr.z - prv[2]*hi.z
                     + piv[3]*hr.w - prv[3]*hi.w;
        }
    }
    #pragma unroll
    for (int j = 0; j < 12; ++j) {
        int h = hq*48 + hg*12 + j;
        int a = (bm*192 + h)*64 + o;
        rh_r[a] = accr[j];
        rh_i[a] = acci[j];
    }
}

// ===========================================================================
// K7 (fused k7+k8): inverse W-transform MFMA + mixer GEMM + channel-LN +
// GELU + shortcut GEMM + GELU.  y never touches HBM.
// grid 4608 = (b*192+h)*3 + wq; 4 waves x 16 pixel rows.
// ===========================================================================
__global__ __launch_bounds__(256) void k7_rec(
    const float* __restrict__ rh_r, const float* __restrict__ rh_i,
    const float* __restrict__ wb_r, const float* __restrict__ wb_i,
    const float* __restrict__ x,
    const uint4* __restrict__ msw,
    const float* __restrict__ mb,
    const float* __restrict__ nrm_g, const float* __restrict__ nrm_b,
    const float* __restrict__ sb,
    float* __restrict__ out)
{
    __shared__ unsigned short aHi[64*104];   // 64 rows x K=96 (+8 pad)
    __shared__ unsigned short aLo[64*104];
    __shared__ uint4 bfrag[1536];            // 12 tiles x [hi:64|lo@+768]
    float* cbuf = (float*)bfrag;             // alias, used after barrier

    int wq = blockIdx.x % 3;
    int bh = blockIdx.x / 3;
    int b = bh / 192, h = bh % 192;
    int w0 = wq * 64;
    int tid = threadIdx.x;
    int wv = __builtin_amdgcn_readfirstlane(tid >> 6);
    int lane = tid & 63, li = lane & 15, quad = lane >> 4;
    int rbase = wv*16;
    int row = rbase + li;

    // ---- A staging: wb tile (64 pix x 48 m, r then i) -> hi/lo bf16
    {
        int pix = bh*192 + w0 + row;
        const float4* pr = (const float4*)(wb_r + pix*48) + quad*3;
        const float4* pi = (const float4*)(wb_i + pix*48) + quad*3;
        #pragma unroll
        for (int q = 0; q < 3; ++q) {
            float4 vr = pr[q];
            float4 vi = pi[q];
            int k0 = quad*12 + q*4;
            float vs[8] = {vr.x, vr.y, vr.z, vr.w, vi.x, vi.y, vi.z, vi.w};
            #pragma unroll
            for (int e = 0; e < 4; ++e) {
                unsigned short h1 = f2bf(vs[e]);
                aHi[row*104 + k0 + e] = h1;
                aLo[row*104 + k0 + e] = f2bf(vs[e] - bf2f(h1));
                unsigned short h2 = f2bf(vs[4+e]);
                aHi[row*104 + 48 + k0 + e] = h2;
                aLo[row*104 + 48 + k0 + e] = f2bf(vs[4+e] - bf2f(h2));
            }
        }
    }
    // ---- B-fragment build: 12 tiles (t = nt*3 + ks)
    for (int t = tid >> 6; t < 12; t += 4) {
        int ks = t % 3;
        int nt = t / 3;
        int o = nt*16 + li;
        unsigned hi8[8], lo8[8];
        #pragma unroll
        for (int j = 0; j < 8; ++j) {
            int kk = ks*32 + quad*8 + j;
            const float* src = (kk < 48) ? rh_r : rh_i;
            int m = (kk < 48) ? kk : kk - 48;
            float v = src[((b*48 + m)*192 + h)*64 + o];
            unsigned short hv = f2bf(v);
            hi8[j] = hv;
            lo8[j] = f2bf(v - bf2f(hv));
        }
        uint4 ph, pl;
        ph.x = hi8[0] | (hi8[1]<<16); ph.y = hi8[2] | (hi8[3]<<16);
        ph.z = hi8[4] | (hi8[5]<<16); ph.w = hi8[6] | (hi8[7]<<16);
        pl.x = lo8[0] | (lo8[1]<<16); pl.y = lo8[2] | (lo8[3]<<16);
        pl.z = lo8[4] | (lo8[5]<<16); pl.w = lo8[6] | (lo8[7]<<16);
        bfrag[t*64 + lane]       = ph;
        bfrag[768 + t*64 + lane] = pl;
    }
    __syncthreads();

    // ---- k7 MFMA: y-tile (64 pix x 64 o) into acc
    union U { uint4 u; bf16x8 b; };
    bf16x8 aH[3], aL[3];
    #pragma unroll
    for (int ks = 0; ks < 3; ++ks) {
        aH[ks] = *(const bf16x8*)&aHi[row*104 + ks*32 + quad*8];
        aL[ks] = *(const bf16x8*)&aLo[row*104 + ks*32 + quad*8];
    }
    f32x4 acc[4];
    #pragma unroll
    for (int nt = 0; nt < 4; ++nt) {
        f32x4 a = {0.f, 0.f, 0.f, 0.f};
        #pragma unroll
        for (int ks = 0; ks < 3; ++ks) {
            int t = nt*3 + ks;
            U bh_, bl_;
            bh_.u = bfrag[t*64 + lane];
            bl_.u = bfrag[768 + t*64 + lane];
            a = __builtin_amdgcn_mfma_f32_16x16x32_bf16(aH[ks], bh_.b, a, 0, 0, 0);
            a = __builtin_amdgcn_mfma_f32_16x16x32_bf16(aH[ks], bl_.b, a, 0, 0, 0);
            a = __builtin_amdgcn_mfma_f32_16x16x32_bf16(aL[ks], bh_.b, a, 0, 0, 0);
        }
        acc[nt] = a;
    }

    // ---- mixer GEMM: write scaled y-tile into wave-private LDS rows (split),
    //      then split-precision MFMA against pre-swizzled mixer weights.
    //      All LDS deps are same-wave (wave-synchronous) -> no barrier.
    const float s = 1.0f / 36864.0f;
    #pragma unroll
    for (int nt = 0; nt < 4; ++nt) {
        int o = nt*16 + li;
        #pragma unroll
        for (int rg = 0; rg < 4; ++rg) {
            int prow = rbase + quad*4 + rg;
            float v = acc[nt][rg] * s;
            unsigned short hv = f2bf(v);
            aHi[prow*104 + o] = hv;
            aLo[prow*104 + o] = f2bf(v - bf2f(hv));
        }
    }
    f32x4 accy[4];
    gemm64s<4, 104>(aHi, aLo, msw, 0, row, quad, lane, accy);

    // ---- channel LN stats (o-dim lives on li x nt within each 16-lane group)
    float vals[4][4];
    float s1[4] = {0,0,0,0}, s2[4] = {0,0,0,0};
    #pragma unroll
    for (int nt = 0; nt < 4; ++nt) {
        int o = nt*16 + li;
        float bv = mb[o];
        #pragma unroll
        for (int rg = 0; rg < 4; ++rg) {
            float v = accy[nt][rg] + bv;
            vals[nt][rg] = v;
            s1[rg] += v;
            s2[rg] = fmaf(v, v, s2[rg]);
        }
    }
    #pragma unroll
    for (int d = 1; d < 16; d <<= 1) {
        #pragma unroll
        for (int rg = 0; rg < 4; ++rg) {
            s1[rg] += __shfl_xor(s1[rg], d, 64);
            s2[rg] += __shfl_xor(s2[rg], d, 64);
        }
    }

    // ---- shortcut GEMM: stage x tile into same wave-private rows
    #pragma unroll
    for (int cc = 0; cc < 16; ++cc) {
        int c = cc*4 + quad;
        float v = x[((b*64 + c)*192 + h)*192 + w0 + row];
        unsigned short hv = f2bf(v);
        aHi[row*104 + c] = hv;
        aLo[row*104 + c] = f2bf(v - bf2f(hv));
    }
    gemm64s<4, 104>(aHi, aLo, msw, 8, row, quad, lane, acc);   // acc = shortcut

    __syncthreads();                       // all bfrag reads done; cbuf aliases
    #pragma unroll
    for (int nt = 0; nt < 4; ++nt) {
        int o = nt*16 + li;
        float gv = nrm_g[o], bev = nrm_b[o], sbv = sb[o];
        #pragma unroll
        for (int rg = 0; rg < 4; ++rg) {
            float mu   = s1[rg] * 0.015625f;
            float rstd = rsqrtf(s2[rg]*0.015625f - mu*mu + LN_EPS);
            float v  = gelu_f(fmaf((vals[nt][rg] - mu)*rstd, gv, bev));
            float sc = acc[nt][rg] + sbv;
            int prow = rbase + quad*4 + rg;
            cbuf[prow*67 + o] = gelu_f(v + sc);
        }
    }
    __syncthreads();
    #pragma unroll
    for (int it = 0; it < 16; ++it) {
        int o = it*4 + (tid >> 6);
        int pix = tid & 63;
        out[((b*64 + o)*192 + h)*192 + w0 + pix] = cbuf[pix*67 + o];
    }
}

extern "C" void kernel_launch(void* const* d_in, const int* in_sizes, int n_in,
                              void* d_out, int out_size, void* d_ws, size_t ws_size,
                              hipStream_t stream)
{
    (void)in_sizes; (void)n_in; (void)out_size; (void)ws_size;
    const float* x    = (const float*)d_in[0];
    const float* wW0  = (const float*)d_in[1];
    const float* wb0  = (const float*)d_in[2];
    const float* wg0  = (const float*)d_in[3];
    const float* wbe0 = (const float*)d_in[4];
    const float* wW1  = (const float*)d_in[5];
    const float* wb1  = (const float*)d_in[6];
    const float* wg1  = (const float*)d_in[7];
    const float* wbe1 = (const float*)d_in[8];
    const float* wW2  = (const float*)d_in[9];
    const float* wb2  = (const float*)d_in[10];
    const float* hW0  = (const float*)d_in[11];
    const float* hb0  = (const float*)d_in[12];
    const float* hg0  = (const float*)d_in[13];
    const float* hbe0 = (const float*)d_in[14];
    const float* hW1  = (const float*)d_in[15];
    const float* hb1  = (const float*)d_in[16];
    const float* hg1  = (const float*)d_in[17];
    const float* hbe1 = (const float*)d_in[18];
    const float* hW2  = (const float*)d_in[19];
    const float* hb2  = (const float*)d_in[20];
    const float* fr   = (const float*)d_in[21];
    const float* fi   = (const float*)d_in[22];
    const float* mw   = (const float*)d_in[23];
    const float* mb   = (const float*)d_in[24];
    const float* ngp  = (const float*)d_in[25];
    const float* nbp  = (const float*)d_in[26];
    const float* sw   = (const float*)d_in[27];
    const float* sb   = (const float*)d_in[28];
    float* out = (float*)d_out;

    float* ws   = (float*)d_ws;
    float* wbr  = ws;                  // 14,155,776  (B,H,W,M2)
    float* wbi  = ws + 14155776;
    float* t_r  = ws + 28311552;       //  4,718,592  (B,H,C,M2)
    float* t_i  = ws + 33030144;
    float* hbr  = ws + 37748736;       //  3,538,944  (B,M2,H,M1)
    float* hbi  = ws + 41287680;
    float* t2r  = ws + 44826624;       //  1,179,648  (B,C,M1,M2); after k5: msw
    float* t2i  = ws + 46006272;
    float* prr  = ws + 47185920;       //  staging (B,M2,C,N) then proc (B,O,M1,M2)
    float* pri  = ws + 48365568;
    float* rhr  = t_r;                 // reuse: t dead after k4b -> rec_h (B,M2,H,O)
    float* rhi  = t_i;
    float* wswb = ws + 49545216;       // MLP weight fragments (former y region)
    uint4* wsw  = (uint4*)wswb;
    uint4* msw  = (uint4*)t2r;         // mixer/shortcut weight fragments

    k0_swizzle<<<dim3(6), dim3(256), 0, stream>>>(wW0, wW1, wW2, hW0, hW1, hW2, wsw);
    k1_mlp_w<<<dim3(4608), dim3(256), 0, stream>>>(x, wW0, wb0, wg0, wbe0,
                                                   wb1, wg1, wbe1, wb2, wsw, wbr, wbi);
    k2_t<<<dim3(1536), dim3(256), 0, stream>>>(x, wbr, wbi, t_r, t_i);
    k3_mlp_h<<<dim3(1152), dim3(256), 0, stream>>>(t_r, hW0, hb0, hg0, hbe0,
                                                   hb1, hg1, hbe1, hb2, wsw + 3584, hbr, hbi);
    k4_t2<<<dim3(384), dim3(256), 0, stream>>>(t_r, t_i, hbr, hbi, prr, pri);
    k4b_tr<<<dim3(512), dim3(256), 0, stream>>>(prr, pri, t2r, t2i);
    k5_proc<<<dim3(288), dim3(256), 0, stream>>>(t2r, t2i, fr, fi, prr, pri);
    k0b_swizzle<<<dim3(2), dim3(256), 0, stream>>>(mw, sw, msw);   // t2 now dead
    k6_rech<<<dim3(1536), dim3(256), 0, stream>>>(prr, pri, hbr, hbi, rhr, rhi);
    k7_rec<<<dim3(4608), dim3(256), 0, stream>>>(rhr, rhi, wbr, wbi,
                                                 x, msw, mb, ngp, nbp, sb, out);
}

// Round 3
// 685.033 us; speedup vs baseline: 1.6733x; 1.0592x over previous
//
#include <hip/hip_runtime.h>
#include <math.h>

#define LN_EPS 1e-5f

typedef short bf16x8 __attribute__((ext_vector_type(8)));
typedef float f32x4  __attribute__((ext_vector_type(4)));

__device__ __forceinline__ float gelu_f(float v) {
    return 0.5f * v * (1.0f + erff(v * 0.70710678118654752f));
}
__device__ __forceinline__ unsigned short f2bf(float f) {
    unsigned u = __float_as_uint(f);
    return (unsigned short)((u + 0x7fffu + ((u >> 16) & 1u)) >> 16);
}
__device__ __forceinline__ float bf2f(unsigned short h) {
    return __uint_as_float(((unsigned)h) << 16);
}

// ===========================================================================
// K0: swizzle MLP weights into MFMA B-fragment order, split hi/lo bf16.
// B[k][n], n = lane&15, k = (lane>>4)*8 + j.  Per tile: 128 uint4 = [hi|lo].
// ===========================================================================
__global__ __launch_bounds__(256) void k0_swizzle(
    const float* __restrict__ wW0, const float* __restrict__ wW1, const float* __restrict__ wW2,
    const float* __restrict__ hW0, const float* __restrict__ hW1, const float* __restrict__ hW2,
    uint4* __restrict__ dst)
{
    int mat = blockIdx.x;
    const float* W; int N, ntiles, base;
    switch (mat) {
      case 0: W=wW0; N=64; ntiles=8;  base=0;    break;
      case 1: W=wW1; N=64; ntiles=8;  base=1024; break;
      case 2: W=wW2; N=96; ntiles=12; base=2048; break;
      case 3: W=hW0; N=64; ntiles=8;  base=3584; break;
      case 4: W=hW1; N=64; ntiles=8;  base=4608; break;
      default:W=hW2; N=96; ntiles=12; base=5632; break;
    }
    int lane = threadIdx.x & 63;
    for (int t = threadIdx.x >> 6; t < ntiles; t += 4) {
        int nt = t >> 1, ks = t & 1;
        int n  = nt*16 + (lane & 15);
        int k0 = ks*32 + (lane >> 4)*8;
        unsigned hi[8], lo[8];
        #pragma unroll
        for (int j = 0; j < 8; ++j) {
            float v = W[(k0 + j)*N + n];
            unsigned short h = f2bf(v);
            hi[j] = h;
            lo[j] = f2bf(v - bf2f(h));
        }
        uint4 ph, pl;
        ph.x = hi[0] | (hi[1]<<16); ph.y = hi[2] | (hi[3]<<16);
        ph.z = hi[4] | (hi[5]<<16); ph.w = hi[6] | (hi[7]<<16);
        pl.x = lo[0] | (lo[1]<<16); pl.y = lo[2] | (lo[3]<<16);
        pl.z = lo[4] | (lo[5]<<16); pl.w = lo[6] | (lo[7]<<16);
        dst[base + t*128 + lane]      = ph;
        dst[base + t*128 + 64 + lane] = pl;
    }
}

// K0b: swizzle mixer/shortcut weights (transposed: B[k=c][n=o] = W[o*64+c]).
__global__ __launch_bounds__(256) void k0b_swizzle(
    const float* __restrict__ mw, const float* __restrict__ sw,
    uint4* __restrict__ dst)
{
    int mat = blockIdx.x;
    const float* W = mat ? sw : mw;
    int base = mat ? 1024 : 0;
    int lane = threadIdx.x & 63;
    for (int t = threadIdx.x >> 6; t < 8; t += 4) {
        int nt = t >> 1, ks = t & 1;
        int n  = nt*16 + (lane & 15);
        int k0 = ks*32 + (lane >> 4)*8;
        unsigned hi[8], lo[8];
        #pragma unroll
        for (int j = 0; j < 8; ++j) {
            float v = W[n*64 + (k0 + j)];
            unsigned short h = f2bf(v);
            hi[j] = h;
            lo[j] = f2bf(v - bf2f(h));
        }
        uint4 ph, pl;
        ph.x = hi[0] | (hi[1]<<16); ph.y = hi[2] | (hi[3]<<16);
        ph.z = hi[4] | (hi[5]<<16); ph.w = hi[6] | (hi[7]<<16);
        pl.x = lo[0] | (lo[1]<<16); pl.y = lo[2] | (lo[3]<<16);
        pl.z = lo[4] | (lo[5]<<16); pl.w = lo[6] | (lo[7]<<16);
        dst[base + t*128 + lane]      = ph;
        dst[base + t*128 + 64 + lane] = pl;
    }
}

// ===========================================================================
// Split-precision MFMA GEMM helper (wave-private 16 rows in LDS).
// ===========================================================================
template<int NT, int STRIDE>
__device__ __forceinline__ void gemm64s(
    const unsigned short* aHi, const unsigned short* aLo,
    const uint4* __restrict__ wsw, int tbase, int row, int quad, int lane,
    f32x4* acc)
{
    union U { uint4 u; bf16x8 b; };
    bf16x8 aH[2], aL[2];
    #pragma unroll
    for (int ks = 0; ks < 2; ++ks) {
        aH[ks] = *(const bf16x8*)&aHi[row*STRIDE + ks*32 + quad*8];
        aL[ks] = *(const bf16x8*)&aLo[row*STRIDE + ks*32 + quad*8];
    }
    #pragma unroll
    for (int nt = 0; nt < NT; ++nt) {
        f32x4 a = {0.f, 0.f, 0.f, 0.f};
        #pragma unroll
        for (int ks = 0; ks < 2; ++ks) {
            int t = tbase + nt*2 + ks;
            U bh, bl;
            bh.u = wsw[t*128 + lane];
            bl.u = wsw[t*128 + 64 + lane];
            a = __builtin_amdgcn_mfma_f32_16x16x32_bf16(aH[ks], bh.b, a, 0, 0, 0);
            a = __builtin_amdgcn_mfma_f32_16x16x32_bf16(aH[ks], bl.b, a, 0, 0, 0);
            a = __builtin_amdgcn_mfma_f32_16x16x32_bf16(aL[ks], bh.b, a, 0, 0, 0);
        }
        acc[nt] = a;
    }
}

template<int NT>
__device__ __forceinline__ void gemm64(
    const unsigned short* aHi, const unsigned short* aLo,
    const uint4* __restrict__ wsw, int tbase, int row, int quad, int lane,
    f32x4* acc)
{
    gemm64s<NT, 72>(aHi, aLo, wsw, tbase, row, quad, lane, acc);
}

__device__ __forceinline__ void ln_gelu_pass(
    f32x4* acc, const float* __restrict__ bias, const float* __restrict__ wrow,
    float coordBase, float coordScale,
    const float* __restrict__ gg, const float* __restrict__ bb,
    unsigned short* aHi, unsigned short* aLo, int rbase, int quad, int li)
{
    float vals[4][4];
    float s1[4] = {0,0,0,0}, s2[4] = {0,0,0,0};
    #pragma unroll
    for (int nt = 0; nt < 4; ++nt) {
        int col = nt*16 + li;
        float bv = bias[col];
        float br = wrow[col];
        #pragma unroll
        for (int rg = 0; rg < 4; ++rg) {
            float coord = (coordBase + (float)(rbase + quad*4 + rg)) * coordScale;
            float v = acc[nt][rg] + fmaf(coord, br, bv);
            vals[nt][rg] = v;
            s1[rg] += v;
            s2[rg] = fmaf(v, v, s2[rg]);
        }
    }
    #pragma unroll
    for (int d = 1; d < 16; d <<= 1) {
        #pragma unroll
        for (int rg = 0; rg < 4; ++rg) {
            s1[rg] += __shfl_xor(s1[rg], d, 64);
            s2[rg] += __shfl_xor(s2[rg], d, 64);
        }
    }
    #pragma unroll
    for (int nt = 0; nt < 4; ++nt) {
        int col = nt*16 + li;
        float gv = gg[col], bev = bb[col];
        #pragma unroll
        for (int rg = 0; rg < 4; ++rg) {
            float mu   = s1[rg] * 0.015625f;
            float rstd = rsqrtf(s2[rg]*0.015625f - mu*mu + LN_EPS);
            float v = gelu_f(fmaf((vals[nt][rg] - mu)*rstd, gv, bev));
            int r = rbase + quad*4 + rg;
            unsigned short hv = f2bf(v);
            aHi[r*72 + col] = hv;
            aLo[r*72 + col] = f2bf(v - bf2f(hv));
        }
    }
}

__device__ __forceinline__ void mlp_body(
    unsigned short* aHi, unsigned short* aLo,
    const uint4* __restrict__ wsw,
    const float* __restrict__ w0row,
    const float* __restrict__ b0, const float* __restrict__ g0, const float* __restrict__ be0,
    const float* __restrict__ b1, const float* __restrict__ g1, const float* __restrict__ be1,
    const float* __restrict__ b2,
    float coordBase,
    float* __restrict__ outR, float* __restrict__ outI, int pixBase)
{
    int tid = threadIdx.x;
    int wv = __builtin_amdgcn_readfirstlane(tid >> 6);
    int lane = tid & 63, li = lane & 15, quad = lane >> 4;
    int rbase = wv*16;
    int row = rbase + li;
    f32x4 acc[6];

    gemm64<4>(aHi, aLo, wsw, 0, row, quad, lane, acc);
    ln_gelu_pass(acc, b0, w0row, coordBase, 1.0f/191.0f, g0, be0, aHi, aLo, rbase, quad, li);
    gemm64<4>(aHi, aLo, wsw, 8, row, quad, lane, acc);
    ln_gelu_pass(acc, b1, b1, 0.f, 0.f, g1, be1, aHi, aLo, rbase, quad, li);
    gemm64<6>(aHi, aLo, wsw, 16, row, quad, lane, acc);
    #pragma unroll
    for (int nt = 0; nt < 6; ++nt) {
        int j = nt*16 + li;
        float bv = b2[j];
        #pragma unroll
        for (int rg = 0; rg < 4; ++rg) {
            float v = acc[nt][rg] + bv;
            int pix = pixBase + rbase + quad*4 + rg;
            if (nt < 3) outR[pix*48 + j]        = v;
            else        outI[pix*48 + (j - 48)] = v;
        }
    }
}

// K1: W-basis MLP.  grid 4608 = (b*192+h)*3 + wq.
__global__ __launch_bounds__(256) void k1_mlp_w(
    const float* __restrict__ x, const float* __restrict__ W0full,
    const float* __restrict__ b0, const float* __restrict__ g0, const float* __restrict__ be0,
    const float* __restrict__ b1, const float* __restrict__ g1, const float* __restrict__ be1,
    const float* __restrict__ b2,
    const uint4* __restrict__ wsw,
    float* __restrict__ wb_r, float* __restrict__ wb_i)
{
    __shared__ unsigned short aHi[64*72];
    __shared__ unsigned short aLo[64*72];
    int tid = threadIdx.x;
    int wv = __builtin_amdgcn_readfirstlane(tid >> 6);
    int lane = tid & 63, li = lane & 15, quad = lane >> 4;
    int wq = blockIdx.x % 3;
    int bh = blockIdx.x / 3;
    int b = bh / 192, h = bh % 192;
    int w0 = wq * 64;
    int r = wv*16 + li;
    #pragma unroll
    for (int cc = 0; cc < 16; ++cc) {
        int c = cc*4 + quad;
        float v = x[((b*64 + c)*192 + h)*192 + (w0 + r)];
        unsigned short hv = f2bf(v);
        aHi[r*72 + c] = hv;
        aLo[r*72 + c] = f2bf(v - bf2f(hv));
    }
    mlp_body(aHi, aLo, wsw, W0full + 64*64, b0, g0, be0, b1, g1, be1, b2,
             (float)w0, wb_r, wb_i, bh*192 + w0);
}

// K3: H-basis MLP.  grid 1152 = (b*48+m)*3 + hq.  t layout (B,H,C,M2).
__global__ __launch_bounds__(256) void k3_mlp_h(
    const float* __restrict__ t_r, const float* __restrict__ W0full,
    const float* __restrict__ b0, const float* __restrict__ g0, const float* __restrict__ be0,
    const float* __restrict__ b1, const float* __restrict__ g1, const float* __restrict__ be1,
    const float* __restrict__ b2,
    const uint4* __restrict__ wsw,
    float* __restrict__ hb_r, float* __restrict__ hb_i)
{
    __shared__ unsigned short aHi[64*72];
    __shared__ unsigned short aLo[64*72];
    int tid = threadIdx.x;
    int wv = __builtin_amdgcn_readfirstlane(tid >> 6);
    int lane = tid & 63, li = lane & 15, quad = lane >> 4;
    int hq = blockIdx.x % 3;
    int bm = blockIdx.x / 3;
    int b = bm / 48, m = bm % 48;
    int h0 = hq * 64;
    int r = wv*16 + li;
    #pragma unroll
    for (int cc = 0; cc < 16; ++cc) {
        int c = cc*4 + quad;
        float v = t_r[((b*192 + h0 + r)*64 + c)*48 + m];
        unsigned short hv = f2bf(v);
        aHi[r*72 + c] = hv;
        aLo[r*72 + c] = f2bf(v - bf2f(hv));
    }
    mlp_body(aHi, aLo, wsw, W0full + 64*64, b0, g0, be0, b1, g1, be1, b2,
             (float)h0, hb_r, hb_i, bm*192 + h0);
}

// ===========================================================================
// K2 (MFMA): per (b,h): T[c][m] = sum_w X[c][w]*WB[w][m].
// Real GEMM M=64(c) N=96(48r|48i) K=192(w), 3 K-chunks of 64.
// grid 1536 = b*192+h; 4 waves x 16 c-rows; out (B,H,C,M2).
// ===========================================================================
__global__ __launch_bounds__(256) void k2_t(
    const float* __restrict__ x,
    const float* __restrict__ wb_r, const float* __restrict__ wb_i,
    float* __restrict__ t_r, float* __restrict__ t_i)
{
    __shared__ unsigned short aHi[64*72];
    __shared__ unsigned short aLo[64*72];
    __shared__ uint4 bfrag[1536];            // 12 tiles x [hi:64|lo@+768]
    int bh = blockIdx.x;
    int b = bh / 192, h = bh % 192;
    int tid = threadIdx.x;
    int wv = __builtin_amdgcn_readfirstlane(tid >> 6);
    int lane = tid & 63, li = lane & 15, quad = lane >> 4;
    int rbase = wv*16;
    int row = rbase + li;

    f32x4 acc[6];
    {
        f32x4 z = {0.f, 0.f, 0.f, 0.f};
        #pragma unroll
        for (int nt = 0; nt < 6; ++nt) acc[nt] = z;
    }
    union U { uint4 u; bf16x8 b8; };

    for (int w0 = 0; w0 < 192; w0 += 64) {
        if (w0) __syncthreads();             // bfrag WAR across chunks
        // A chunk: wave-private rows c, k = w-offset (coalesced float4 loads)
        {
            const float4* srow = (const float4*)(x + ((b*64 + row)*192 + h)*192 + w0) + quad*4;
            #pragma unroll
            for (int q = 0; q < 4; ++q) {
                float4 v4 = srow[q];
                float vv[4] = {v4.x, v4.y, v4.z, v4.w};
                int k0 = quad*16 + q*4;
                #pragma unroll
                for (int e = 0; e < 4; ++e) {
                    unsigned short hv = f2bf(vv[e]);
                    aHi[row*72 + k0 + e] = hv;
                    aLo[row*72 + k0 + e] = f2bf(vv[e] - bf2f(hv));
                }
            }
        }
        // B chunk: 12 tiles (t = nt*2+ks), cols n<48 -> wb_r, n>=48 -> wb_i
        for (int t = tid >> 6; t < 12; t += 4) {
            int nt = t >> 1, ks = t & 1;
            const float* src = (nt < 3) ? wb_r : wb_i;
            int col = (nt < 3 ? nt : nt - 3)*16 + li;
            const float* sp = src + (bh*192 + w0 + ks*32 + quad*8)*48 + col;
            unsigned hi8[8], lo8[8];
            #pragma unroll
            for (int j = 0; j < 8; ++j) {
                float v = sp[j*48];
                unsigned short hv = f2bf(v);
                hi8[j] = hv;
                lo8[j] = f2bf(v - bf2f(hv));
            }
            uint4 ph, pl;
            ph.x = hi8[0] | (hi8[1]<<16); ph.y = hi8[2] | (hi8[3]<<16);
            ph.z = hi8[4] | (hi8[5]<<16); ph.w = hi8[6] | (hi8[7]<<16);
            pl.x = lo8[0] | (lo8[1]<<16); pl.y = lo8[2] | (lo8[3]<<16);
            pl.z = lo8[4] | (lo8[5]<<16); pl.w = lo8[6] | (lo8[7]<<16);
            bfrag[t*64 + lane]       = ph;
            bfrag[768 + t*64 + lane] = pl;
        }
        __syncthreads();
        bf16x8 aH[2], aL[2];
        #pragma unroll
        for (int ks = 0; ks < 2; ++ks) {
            aH[ks] = *(const bf16x8*)&aHi[row*72 + ks*32 + quad*8];
            aL[ks] = *(const bf16x8*)&aLo[row*72 + ks*32 + quad*8];
        }
        #pragma unroll
        for (int nt = 0; nt < 6; ++nt) {
            f32x4 a = acc[nt];
            #pragma unroll
            for (int ks = 0; ks < 2; ++ks) {
                int t = nt*2 + ks;
                U bh_, bl_;
                bh_.u = bfrag[t*64 + lane];
                bl_.u = bfrag[768 + t*64 + lane];
                a = __builtin_amdgcn_mfma_f32_16x16x32_bf16(aH[ks], bh_.b8, a, 0, 0, 0);
                a = __builtin_amdgcn_mfma_f32_16x16x32_bf16(aH[ks], bl_.b8, a, 0, 0, 0);
                a = __builtin_amdgcn_mfma_f32_16x16x32_bf16(aL[ks], bh_.b8, a, 0, 0, 0);
            }
            acc[nt] = a;
        }
    }
    #pragma unroll
    for (int nt = 0; nt < 6; ++nt) {
        #pragma unroll
        for (int rg = 0; rg < 4; ++rg) {
            int c = rbase + quad*4 + rg;
            float v = acc[nt][rg];
            if (nt < 3) t_r[(bh*64 + c)*48 + nt*16 + li]       = v;
            else        t_i[(bh*64 + c)*48 + (nt - 3)*16 + li] = v;
        }
    }
}

// ===========================================================================
// K4 (MFMA): per (b,m): T2[c][n] = sum_h T[c][h]*HB[h][n] (complex).
// Real GEMM: A = [Tr | Ti] (64x384), B = [[Hbr,Hbi],[-Hbi,Hbr]] (384x96),
// cols n<48 -> t2_r, n>=48 -> t2_i.  Writes FINAL layout (B,C,N,M2) directly
// (k4b transpose eliminated).  grid 384 = b*48+m; 4 waves x 16 c-rows.
// ===========================================================================
__global__ __launch_bounds__(256) void k4_t2(
    const float* __restrict__ t_r, const float* __restrict__ t_i,
    const float* __restrict__ hb_r, const float* __restrict__ hb_i,
    float* __restrict__ t2_r, float* __restrict__ t2_i)
{
    __shared__ unsigned short aHi[64*72];
    __shared__ unsigned short aLo[64*72];
    __shared__ uint4 bfrag[1536];
    int bm = blockIdx.x;
    int b = bm / 48, m = bm % 48;
    int tid = threadIdx.x;
    int wv = __builtin_amdgcn_readfirstlane(tid >> 6);
    int lane = tid & 63, li = lane & 15, quad = lane >> 4;
    int rbase = wv*16;
    int row = rbase + li;

    f32x4 acc[6];
    {
        f32x4 z = {0.f, 0.f, 0.f, 0.f};
        #pragma unroll
        for (int nt = 0; nt < 6; ++nt) acc[nt] = z;
    }
    union U { uint4 u; bf16x8 b8; };

    for (int p = 0; p < 6; ++p) {
        bool realp = (p < 3);
        int h0 = (p % 3) * 64;
        if (p) __syncthreads();
        // A chunk: wave-private rows c, k = h-offset (strided gathers)
        {
            const float* tsrc = (realp ? t_r : t_i)
                              + ((b*192 + h0)*64 + row)*48 + m;
            #pragma unroll
            for (int q = 0; q < 16; ++q) {
                int k = quad*16 + q;
                float v = tsrc[k*3072];
                unsigned short hv = f2bf(v);
                aHi[row*72 + k] = hv;
                aLo[row*72 + k] = f2bf(v - bf2f(hv));
            }
        }
        // B chunk: 12 tiles from hb (with conj/sign structure)
        for (int t = tid >> 6; t < 12; t += 4) {
            int nt = t >> 1, ks = t & 1;
            const float* src;
            int col;
            float sgn = 1.f;
            if (realp) {
                if (nt < 3) { src = hb_r; col = nt*16 + li; }
                else        { src = hb_i; col = (nt - 3)*16 + li; }
            } else {
                if (nt < 3) { src = hb_i; col = nt*16 + li; sgn = -1.f; }
                else        { src = hb_r; col = (nt - 3)*16 + li; }
            }
            const float* sp = src + (bm*192 + h0 + ks*32 + quad*8)*48 + col;
            unsigned hi8[8], lo8[8];
            #pragma unroll
            for (int j = 0; j < 8; ++j) {
                float v = sgn * sp[j*48];
                unsigned short hv = f2bf(v);
                hi8[j] = hv;
                lo8[j] = f2bf(v - bf2f(hv));
            }
            uint4 ph, pl;
            ph.x = hi8[0] | (hi8[1]<<16); ph.y = hi8[2] | (hi8[3]<<16);
            ph.z = hi8[4] | (hi8[5]<<16); ph.w = hi8[6] | (hi8[7]<<16);
            pl.x = lo8[0] | (lo8[1]<<16); pl.y = lo8[2] | (lo8[3]<<16);
            pl.z = lo8[4] | (lo8[5]<<16); pl.w = lo8[6] | (lo8[7]<<16);
            bfrag[t*64 + lane]       = ph;
            bfrag[768 + t*64 + lane] = pl;
        }
        __syncthreads();
        bf16x8 aH[2], aL[2];
        #pragma unroll
        for (int ks = 0; ks < 2; ++ks) {
            aH[ks] = *(const bf16x8*)&aHi[row*72 + ks*32 + quad*8];
            aL[ks] = *(const bf16x8*)&aLo[row*72 + ks*32 + quad*8];
        }
        #pragma unroll
        for (int nt = 0; nt < 6; ++nt) {
            f32x4 a = acc[nt];
            #pragma unroll
            for (int ks = 0; ks < 2; ++ks) {
                int t = nt*2 + ks;
                U bh_, bl_;
                bh_.u = bfrag[t*64 + lane];
                bl_.u = bfrag[768 + t*64 + lane];
                a = __builtin_amdgcn_mfma_f32_16x16x32_bf16(aH[ks], bh_.b8, a, 0, 0, 0);
                a = __builtin_amdgcn_mfma_f32_16x16x32_bf16(aH[ks], bl_.b8, a, 0, 0, 0);
                a = __builtin_amdgcn_mfma_f32_16x16x32_bf16(aL[ks], bh_.b8, a, 0, 0, 0);
            }
            acc[nt] = a;
        }
    }
    // store directly in (B,C,N,M2)
    #pragma unroll
    for (int nt = 0; nt < 6; ++nt) {
        #pragma unroll
        for (int rg = 0; rg < 4; ++rg) {
            int c = rbase + quad*4 + rg;
            float v = acc[nt][rg];
            if (nt < 3) t2_r[((b*64 + c)*48 + nt*16 + li)*48 + m]       = v;
            else        t2_i[((b*64 + c)*48 + (nt - 3)*16 + li)*48 + m] = v;
        }
    }
}

// K5: proc[b,o,nm] = sum_i t2[b,i,nm]*Wf[o,i,nm].  grid 288.
__global__ __launch_bounds__(256) void k5_proc(
    const float* __restrict__ t2_r, const float* __restrict__ t2_i,
    const float* __restrict__ fr, const float* __restrict__ fi,
    float* __restrict__ proc_r, float* __restrict__ proc_i)
{
    int og = blockIdx.x & 31;
    int ch = blockIdx.x >> 5;
    int nm = ch*256 + threadIdx.x;
    int o0 = og*2;
    float p0r[8], p0i[8], p1r[8], p1i[8];
    #pragma unroll
    for (int bb = 0; bb < 8; ++bb) { p0r[bb]=0.f; p0i[bb]=0.f; p1r[bb]=0.f; p1i[bb]=0.f; }
    for (int i = 0; i < 64; ++i) {
        float w0r = fr[(o0*64 + i)*2304 + nm];
        float w0i = fi[(o0*64 + i)*2304 + nm];
        float w1r = fr[((o0+1)*64 + i)*2304 + nm];
        float w1i = fi[((o0+1)*64 + i)*2304 + nm];
        #pragma unroll
        for (int bb = 0; bb < 8; ++bb) {
            float tr = t2_r[(bb*64 + i)*2304 + nm];
            float ti = t2_i[(bb*64 + i)*2304 + nm];
            p0r[bb] = fmaf(tr, w0r, fmaf(-ti, w0i, p0r[bb]));
            p0i[bb] = fmaf(tr, w0i, fmaf( ti, w0r, p0i[bb]));
            p1r[bb] = fmaf(tr, w1r, fmaf(-ti, w1i, p1r[bb]));
            p1i[bb] = fmaf(tr, w1i, fmaf( ti, w1r, p1i[bb]));
        }
    }
    #pragma unroll
    for (int bb = 0; bb < 8; ++bb) {
        proc_r[(bb*64 + o0)*2304 + nm]     = p0r[bb];
        proc_i[(bb*64 + o0)*2304 + nm]     = p0i[bb];
        proc_r[(bb*64 + o0 + 1)*2304 + nm] = p1r[bb];
        proc_i[(bb*64 + o0 + 1)*2304 + nm] = p1i[bb];
    }
}

// ===========================================================================
// K6 (MFMA): rec_h[h][o] = sum_n proc[b,o,n,m]*conj(hb[b,m,h,n]).
// A = [Hbr | Hbi] (64h x 96), two B passes:
//   real: k<48 -> Pr[o][k], k>=48 -> Pi[o][k-48]
//   imag: k<48 -> Pi[o][k], k>=48 -> -Pr[o][k-48]
// grid 1152 = bm*3 + hq; 4 waves x 16 h-rows.  rec_h stored (B,M2,H,O).
// ===========================================================================
__global__ __launch_bounds__(256) void k6_rech(
    const float* __restrict__ proc_r, const float* __restrict__ proc_i,
    const float* __restrict__ hb_r, const float* __restrict__ hb_i,
    float* __restrict__ rh_r, float* __restrict__ rh_i)
{
    __shared__ unsigned short aHi[64*104];
    __shared__ unsigned short aLo[64*104];
    __shared__ uint4 bfrag[1536];
    int hq = blockIdx.x % 3;
    int bm = blockIdx.x / 3;
    int b = bm / 48, m = bm % 48;
    int h0 = hq * 64;
    int tid = threadIdx.x;
    int wv = __builtin_amdgcn_readfirstlane(tid >> 6);
    int lane = tid & 63, li = lane & 15, quad = lane >> 4;
    int rbase = wv*16;
    int row = rbase + li;

    // A staging: hb row tile (64 h x 48r|48i) -> hi/lo bf16 (k7 pattern)
    {
        int hr = bm*192 + h0 + row;
        const float4* pr = (const float4*)(hb_r + hr*48) + quad*3;
        const float4* pi = (const float4*)(hb_i + hr*48) + quad*3;
        #pragma unroll
        for (int q = 0; q < 3; ++q) {
            float4 vr = pr[q];
            float4 vi = pi[q];
            int k0 = quad*12 + q*4;
            float vs[8] = {vr.x, vr.y, vr.z, vr.w, vi.x, vi.y, vi.z, vi.w};
            #pragma unroll
            for (int e = 0; e < 4; ++e) {
                unsigned short h1 = f2bf(vs[e]);
                aHi[row*104 + k0 + e] = h1;
                aLo[row*104 + k0 + e] = f2bf(vs[e] - bf2f(h1));
                unsigned short h2 = f2bf(vs[4+e]);
                aHi[row*104 + 48 + k0 + e] = h2;
                aLo[row*104 + 48 + k0 + e] = f2bf(vs[4+e] - bf2f(h2));
            }
        }
    }
    union U { uint4 u; bf16x8 b8; };
    bf16x8 aH[3], aL[3];
    #pragma unroll
    for (int ks = 0; ks < 3; ++ks) {
        aH[ks] = *(const bf16x8*)&aHi[row*104 + ks*32 + quad*8];
        aL[ks] = *(const bf16x8*)&aLo[row*104 + ks*32 + quad*8];
    }

    f32x4 accR[4], accI[4];
    for (int pass = 0; pass < 2; ++pass) {
        if (pass) __syncthreads();           // bfrag WAR between passes
        for (int t = tid >> 6; t < 12; t += 4) {
            int ks = t % 3;
            int nt = t / 3;
            int o = nt*16 + li;
            const float* base_lo = pass ? proc_i : proc_r;   // k<48 source
            const float* base_hi = pass ? proc_r : proc_i;   // k>=48 source
            float sgn_hi = pass ? -1.f : 1.f;
            unsigned hi8[8], lo8[8];
            #pragma unroll
            for (int j = 0; j < 8; ++j) {
                int kk = ks*32 + quad*8 + j;
                float v;
                if (kk < 48) v = base_lo[(b*64 + o)*2304 + kk*48 + m];
                else         v = sgn_hi * base_hi[(b*64 + o)*2304 + (kk - 48)*48 + m];
                unsigned short hv = f2bf(v);
                hi8[j] = hv;
                lo8[j] = f2bf(v - bf2f(hv));
            }
            uint4 ph, pl;
            ph.x = hi8[0] | (hi8[1]<<16); ph.y = hi8[2] | (hi8[3]<<16);
            ph.z = hi8[4] | (hi8[5]<<16); ph.w = hi8[6] | (hi8[7]<<16);
            pl.x = lo8[0] | (lo8[1]<<16); pl.y = lo8[2] | (lo8[3]<<16);
            pl.z = lo8[4] | (lo8[5]<<16); pl.w = lo8[6] | (lo8[7]<<16);
            bfrag[t*64 + lane]       = ph;
            bfrag[768 + t*64 + lane] = pl;
        }
        __syncthreads();
        f32x4* acc = pass ? accI : accR;
        #pragma unroll
        for (int nt = 0; nt < 4; ++nt) {
            f32x4 a = {0.f, 0.f, 0.f, 0.f};
            #pragma unroll
            for (int ks = 0; ks < 3; ++ks) {
                int t = nt*3 + ks;
                U bh_, bl_;
                bh_.u = bfrag[t*64 + lane];
                bl_.u = bfrag[768 + t*64 + lane];
                a = __builtin_amdgcn_mfma_f32_16x16x32_bf16(aH[ks], bh_.b8, a, 0, 0, 0);
                a = __builtin_amdgcn_mfma_f32_16x16x32_bf16(aH[ks], bl_.b8, a, 0, 0, 0);
                a = __builtin_amdgcn_mfma_f32_16x16x32_bf16(aL[ks], bh_.b8, a, 0, 0, 0);
            }
            acc[nt] = a;
        }
    }
    #pragma unroll
    for (int nt = 0; nt < 4; ++nt) {
        int o = nt*16 + li;
        #pragma unroll
        for (int rg = 0; rg < 4; ++rg) {
            int hrow = h0 + rbase + quad*4 + rg;
            int a = (bm*192 + hrow)*64 + o;
            rh_r[a] = accR[nt][rg];
            rh_i[a] = accI[nt][rg];
        }
    }
}

// ===========================================================================
// K7 (fused k7+k8): inverse W-transform MFMA + mixer GEMM + channel-LN +
// GELU + shortcut GEMM + GELU.  y never touches HBM.
// grid 4608 = (b*192+h)*3 + wq; 4 waves x 16 pixel rows.
// ===========================================================================
__global__ __launch_bounds__(256) void k7_rec(
    const float* __restrict__ rh_r, const float* __restrict__ rh_i,
    const float* __restrict__ wb_r, const float* __restrict__ wb_i,
    const float* __restrict__ x,
    const uint4* __restrict__ msw,
    const float* __restrict__ mb,
    const float* __restrict__ nrm_g, const float* __restrict__ nrm_b,
    const float* __restrict__ sb,
    float* __restrict__ out)
{
    __shared__ unsigned short aHi[64*104];   // 64 rows x K=96 (+8 pad)
    __shared__ unsigned short aLo[64*104];
    __shared__ uint4 bfrag[1536];            // 12 tiles x [hi:64|lo@+768]
    float* cbuf = (float*)bfrag;             // alias, used after barrier

    int wq = blockIdx.x % 3;
    int bh = blockIdx.x / 3;
    int b = bh / 192, h = bh % 192;
    int w0 = wq * 64;
    int tid = threadIdx.x;
    int wv = __builtin_amdgcn_readfirstlane(tid >> 6);
    int lane = tid & 63, li = lane & 15, quad = lane >> 4;
    int rbase = wv*16;
    int row = rbase + li;

    // ---- A staging: wb tile (64 pix x 48 m, r then i) -> hi/lo bf16
    {
        int pix = bh*192 + w0 + row;
        const float4* pr = (const float4*)(wb_r + pix*48) + quad*3;
        const float4* pi = (const float4*)(wb_i + pix*48) + quad*3;
        #pragma unroll
        for (int q = 0; q < 3; ++q) {
            float4 vr = pr[q];
            float4 vi = pi[q];
            int k0 = quad*12 + q*4;
            float vs[8] = {vr.x, vr.y, vr.z, vr.w, vi.x, vi.y, vi.z, vi.w};
            #pragma unroll
            for (int e = 0; e < 4; ++e) {
                unsigned short h1 = f2bf(vs[e]);
                aHi[row*104 + k0 + e] = h1;
                aLo[row*104 + k0 + e] = f2bf(vs[e] - bf2f(h1));
                unsigned short h2 = f2bf(vs[4+e]);
                aHi[row*104 + 48 + k0 + e] = h2;
                aLo[row*104 + 48 + k0 + e] = f2bf(vs[4+e] - bf2f(h2));
            }
        }
    }
    // ---- B-fragment build: 12 tiles (t = nt*3 + ks)
    for (int t = tid >> 6; t < 12; t += 4) {
        int ks = t % 3;
        int nt = t / 3;
        int o = nt*16 + li;
        unsigned hi8[8], lo8[8];
        #pragma unroll
        for (int j = 0; j < 8; ++j) {
            int kk = ks*32 + quad*8 + j;
            const float* src = (kk < 48) ? rh_r : rh_i;
            int m = (kk < 48) ? kk : kk - 48;
            float v = src[((b*48 + m)*192 + h)*64 + o];
            unsigned short hv = f2bf(v);
            hi8[j] = hv;
            lo8[j] = f2bf(v - bf2f(hv));
        }
        uint4 ph, pl;
        ph.x = hi8[0] | (hi8[1]<<16); ph.y = hi8[2] | (hi8[3]<<16);
        ph.z = hi8[4] | (hi8[5]<<16); ph.w = hi8[6] | (hi8[7]<<16);
        pl.x = lo8[0] | (lo8[1]<<16); pl.y = lo8[2] | (lo8[3]<<16);
        pl.z = lo8[4] | (lo8[5]<<16); pl.w = lo8[6] | (lo8[7]<<16);
        bfrag[t*64 + lane]       = ph;
        bfrag[768 + t*64 + lane] = pl;
    }
    __syncthreads();

    // ---- k7 MFMA: y-tile (64 pix x 64 o) into acc
    union U { uint4 u; bf16x8 b; };
    bf16x8 aH[3], aL[3];
    #pragma unroll
    for (int ks = 0; ks < 3; ++ks) {
        aH[ks] = *(const bf16x8*)&aHi[row*104 + ks*32 + quad*8];
        aL[ks] = *(const bf16x8*)&aLo[row*104 + ks*32 + quad*8];
    }
    f32x4 acc[4];
    #pragma unroll
    for (int nt = 0; nt < 4; ++nt) {
        f32x4 a = {0.f, 0.f, 0.f, 0.f};
        #pragma unroll
        for (int ks = 0; ks < 3; ++ks) {
            int t = nt*3 + ks;
            U bh_, bl_;
            bh_.u = bfrag[t*64 + lane];
            bl_.u = bfrag[768 + t*64 + lane];
            a = __builtin_amdgcn_mfma_f32_16x16x32_bf16(aH[ks], bh_.b, a, 0, 0, 0);
            a = __builtin_amdgcn_mfma_f32_16x16x32_bf16(aH[ks], bl_.b, a, 0, 0, 0);
            a = __builtin_amdgcn_mfma_f32_16x16x32_bf16(aL[ks], bh_.b, a, 0, 0, 0);
        }
        acc[nt] = a;
    }

    // ---- mixer GEMM: write scaled y-tile into wave-private LDS rows (split),
    //      then split-precision MFMA against pre-swizzled mixer weights.
    const float s = 1.0f / 36864.0f;
    #pragma unroll
    for (int nt = 0; nt < 4; ++nt) {
        int o = nt*16 + li;
        #pragma unroll
        for (int rg = 0; rg < 4; ++rg) {
            int prow = rbase + quad*4 + rg;
            float v = acc[nt][rg] * s;
            unsigned short hv = f2bf(v);
            aHi[prow*104 + o] = hv;
            aLo[prow*104 + o] = f2bf(v - bf2f(hv));
        }
    }
    f32x4 accy[4];
    gemm64s<4, 104>(aHi, aLo, msw, 0, row, quad, lane, accy);

    // ---- channel LN stats
    float vals[4][4];
    float s1[4] = {0,0,0,0}, s2[4] = {0,0,0,0};
    #pragma unroll
    for (int nt = 0; nt < 4; ++nt) {
        int o = nt*16 + li;
        float bv = mb[o];
        #pragma unroll
        for (int rg = 0; rg < 4; ++rg) {
            float v = accy[nt][rg] + bv;
            vals[nt][rg] = v;
            s1[rg] += v;
            s2[rg] = fmaf(v, v, s2[rg]);
        }
    }
    #pragma unroll
    for (int d = 1; d < 16; d <<= 1) {
        #pragma unroll
        for (int rg = 0; rg < 4; ++rg) {
            s1[rg] += __shfl_xor(s1[rg], d, 64);
            s2[rg] += __shfl_xor(s2[rg], d, 64);
        }
    }

    // ---- shortcut GEMM: stage x tile into same wave-private rows
    #pragma unroll
    for (int cc = 0; cc < 16; ++cc) {
        int c = cc*4 + quad;
        float v = x[((b*64 + c)*192 + h)*192 + w0 + row];
        unsigned short hv = f2bf(v);
        aHi[row*104 + c] = hv;
        aLo[row*104 + c] = f2bf(v - bf2f(hv));
    }
    gemm64s<4, 104>(aHi, aLo, msw, 8, row, quad, lane, acc);   // acc = shortcut

    __syncthreads();                       // all bfrag reads done; cbuf aliases
    #pragma unroll
    for (int nt = 0; nt < 4; ++nt) {
        int o = nt*16 + li;
        float gv = nrm_g[o], bev = nrm_b[o], sbv = sb[o];
        #pragma unroll
        for (int rg = 0; rg < 4; ++rg) {
            float mu   = s1[rg] * 0.015625f;
            float rstd = rsqrtf(s2[rg]*0.015625f - mu*mu + LN_EPS);
            float v  = gelu_f(fmaf((vals[nt][rg] - mu)*rstd, gv, bev));
            float sc = acc[nt][rg] + sbv;
            int prow = rbase + quad*4 + rg;
            cbuf[prow*67 + o] = gelu_f(v + sc);
        }
    }
    __syncthreads();
    #pragma unroll
    for (int it = 0; it < 16; ++it) {
        int o = it*4 + (tid >> 6);
        int pix = tid & 63;
        out[((b*64 + o)*192 + h)*192 + w0 + pix] = cbuf[pix*67 + o];
    }
}

extern "C" void kernel_launch(void* const* d_in, const int* in_sizes, int n_in,
                              void* d_out, int out_size, void* d_ws, size_t ws_size,
                              hipStream_t stream)
{
    (void)in_sizes; (void)n_in; (void)out_size; (void)ws_size;
    const float* x    = (const float*)d_in[0];
    const float* wW0  = (const float*)d_in[1];
    const float* wb0  = (const float*)d_in[2];
    const float* wg0  = (const float*)d_in[3];
    const float* wbe0 = (const float*)d_in[4];
    const float* wW1  = (const float*)d_in[5];
    const float* wb1  = (const float*)d_in[6];
    const float* wg1  = (const float*)d_in[7];
    const float* wbe1 = (const float*)d_in[8];
    const float* wW2  = (const float*)d_in[9];
    const float* wb2  = (const float*)d_in[10];
    const float* hW0  = (const float*)d_in[11];
    const float* hb0  = (const float*)d_in[12];
    const float* hg0  = (const float*)d_in[13];
    const float* hbe0 = (const float*)d_in[14];
    const float* hW1  = (const float*)d_in[15];
    const float* hb1  = (const float*)d_in[16];
    const float* hg1  = (const float*)d_in[17];
    const float* hbe1 = (const float*)d_in[18];
    const float* hW2  = (const float*)d_in[19];
    const float* hb2  = (const float*)d_in[20];
    const float* fr   = (const float*)d_in[21];
    const float* fi   = (const float*)d_in[22];
    const float* mw   = (const float*)d_in[23];
    const float* mb   = (const float*)d_in[24];
    const float* ngp  = (const float*)d_in[25];
    const float* nbp  = (const float*)d_in[26];
    const float* sw   = (const float*)d_in[27];
    const float* sb   = (const float*)d_in[28];
    float* out = (float*)d_out;

    float* ws   = (float*)d_ws;
    float* wbr  = ws;                  // 14,155,776  (B,H,W,M2)
    float* wbi  = ws + 14155776;
    float* t_r  = ws + 28311552;       //  4,718,592  (B,H,C,M2)
    float* t_i  = ws + 33030144;
    float* hbr  = ws + 37748736;       //  3,538,944  (B,M2,H,M1)
    float* hbi  = ws + 41287680;
    float* t2r  = ws + 44826624;       //  1,179,648  (B,C,N,M2); after k5: msw
    float* t2i  = ws + 46006272;
    float* prr  = ws + 47185920;       //  proc (B,O,M1,M2)
    float* pri  = ws + 48365568;
    float* rhr  = t_r;                 // reuse: t dead after k4 -> rec_h (B,M2,H,O)
    float* rhi  = t_i;
    float* wswb = ws + 49545216;       // MLP weight fragments
    uint4* wsw  = (uint4*)wswb;
    uint4* msw  = (uint4*)t2r;         // mixer/shortcut weight fragments

    k0_swizzle<<<dim3(6), dim3(256), 0, stream>>>(wW0, wW1, wW2, hW0, hW1, hW2, wsw);
    k1_mlp_w<<<dim3(4608), dim3(256), 0, stream>>>(x, wW0, wb0, wg0, wbe0,
                                                   wb1, wg1, wbe1, wb2, wsw, wbr, wbi);
    k2_t<<<dim3(1536), dim3(256), 0, stream>>>(x, wbr, wbi, t_r, t_i);
    k3_mlp_h<<<dim3(1152), dim3(256), 0, stream>>>(t_r, hW0, hb0, hg0, hbe0,
                                                   hb1, hg1, hbe1, hb2, wsw + 3584, hbr, hbi);
    k4_t2<<<dim3(384), dim3(256), 0, stream>>>(t_r, t_i, hbr, hbi, t2r, t2i);
    k5_proc<<<dim3(288), dim3(256), 0, stream>>>(t2r, t2i, fr, fi, prr, pri);
    k0b_swizzle<<<dim3(2), dim3(256), 0, stream>>>(mw, sw, msw);   // t2 now dead
    k6_rech<<<dim3(1152), dim3(256), 0, stream>>>(prr, pri, hbr, hbi, rhr, rhi);
    k7_rec<<<dim3(4608), dim3(256), 0, stream>>>(rhr, rhi, wbr, wbi,
                                                 x, msw, mb, ngp, nbp, sb, out);
}

// Round 4
// 567.811 us; speedup vs baseline: 2.0188x; 1.2064x over previous
//
#include <hip/hip_runtime.h>
#include <math.h>

#define LN_EPS 1e-5f

typedef short bf16x8 __attribute__((ext_vector_type(8)));
typedef float f32x4  __attribute__((ext_vector_type(4)));

__device__ __forceinline__ float gelu_f(float v) {
    return 0.5f * v * (1.0f + erff(v * 0.70710678118654752f));
}
__device__ __forceinline__ unsigned short f2bf(float f) {
    unsigned u = __float_as_uint(f);
    return (unsigned short)((u + 0x7fffu + ((u >> 16) & 1u)) >> 16);
}
__device__ __forceinline__ float bf2f(unsigned short h) {
    return __uint_as_float(((unsigned)h) << 16);
}

// ===========================================================================
// K0: swizzle MLP weights into MFMA B-fragment order, split hi/lo bf16.
// ===========================================================================
__global__ __launch_bounds__(256) void k0_swizzle(
    const float* __restrict__ wW0, const float* __restrict__ wW1, const float* __restrict__ wW2,
    const float* __restrict__ hW0, const float* __restrict__ hW1, const float* __restrict__ hW2,
    uint4* __restrict__ dst)
{
    int mat = blockIdx.x;
    const float* W; int N, ntiles, base;
    switch (mat) {
      case 0: W=wW0; N=64; ntiles=8;  base=0;    break;
      case 1: W=wW1; N=64; ntiles=8;  base=1024; break;
      case 2: W=wW2; N=96; ntiles=12; base=2048; break;
      case 3: W=hW0; N=64; ntiles=8;  base=3584; break;
      case 4: W=hW1; N=64; ntiles=8;  base=4608; break;
      default:W=hW2; N=96; ntiles=12; base=5632; break;
    }
    int lane = threadIdx.x & 63;
    for (int t = threadIdx.x >> 6; t < ntiles; t += 4) {
        int nt = t >> 1, ks = t & 1;
        int n  = nt*16 + (lane & 15);
        int k0 = ks*32 + (lane >> 4)*8;
        unsigned hi[8], lo[8];
        #pragma unroll
        for (int j = 0; j < 8; ++j) {
            float v = W[(k0 + j)*N + n];
            unsigned short h = f2bf(v);
            hi[j] = h;
            lo[j] = f2bf(v - bf2f(h));
        }
        uint4 ph, pl;
        ph.x = hi[0] | (hi[1]<<16); ph.y = hi[2] | (hi[3]<<16);
        ph.z = hi[4] | (hi[5]<<16); ph.w = hi[6] | (hi[7]<<16);
        pl.x = lo[0] | (lo[1]<<16); pl.y = lo[2] | (lo[3]<<16);
        pl.z = lo[4] | (lo[5]<<16); pl.w = lo[6] | (lo[7]<<16);
        dst[base + t*128 + lane]      = ph;
        dst[base + t*128 + 64 + lane] = pl;
    }
}

// K0b: swizzle mixer/shortcut weights (transposed: B[k=c][n=o] = W[o*64+c]).
__global__ __launch_bounds__(256) void k0b_swizzle(
    const float* __restrict__ mw, const float* __restrict__ sw,
    uint4* __restrict__ dst)
{
    int mat = blockIdx.x;
    const float* W = mat ? sw : mw;
    int base = mat ? 1024 : 0;
    int lane = threadIdx.x & 63;
    for (int t = threadIdx.x >> 6; t < 8; t += 4) {
        int nt = t >> 1, ks = t & 1;
        int n  = nt*16 + (lane & 15);
        int k0 = ks*32 + (lane >> 4)*8;
        unsigned hi[8], lo[8];
        #pragma unroll
        for (int j = 0; j < 8; ++j) {
            float v = W[n*64 + (k0 + j)];
            unsigned short h = f2bf(v);
            hi[j] = h;
            lo[j] = f2bf(v - bf2f(h));
        }
        uint4 ph, pl;
        ph.x = hi[0] | (hi[1]<<16); ph.y = hi[2] | (hi[3]<<16);
        ph.z = hi[4] | (hi[5]<<16); ph.w = hi[6] | (hi[7]<<16);
        pl.x = lo[0] | (lo[1]<<16); pl.y = lo[2] | (lo[3]<<16);
        pl.z = lo[4] | (lo[5]<<16); pl.w = lo[6] | (lo[7]<<16);
        dst[base + t*128 + lane]      = ph;
        dst[base + t*128 + 64 + lane] = pl;
    }
}

// ===========================================================================
// Split-precision MFMA GEMM helper (wave-private 16 rows in LDS).
// ===========================================================================
template<int NT, int STRIDE>
__device__ __forceinline__ void gemm64s(
    const unsigned short* aHi, const unsigned short* aLo,
    const uint4* __restrict__ wsw, int tbase, int row, int quad, int lane,
    f32x4* acc)
{
    union U { uint4 u; bf16x8 b; };
    bf16x8 aH[2], aL[2];
    #pragma unroll
    for (int ks = 0; ks < 2; ++ks) {
        aH[ks] = *(const bf16x8*)&aHi[row*STRIDE + ks*32 + quad*8];
        aL[ks] = *(const bf16x8*)&aLo[row*STRIDE + ks*32 + quad*8];
    }
    #pragma unroll
    for (int nt = 0; nt < NT; ++nt) {
        f32x4 a = {0.f, 0.f, 0.f, 0.f};
        #pragma unroll
        for (int ks = 0; ks < 2; ++ks) {
            int t = tbase + nt*2 + ks;
            U bh, bl;
            bh.u = wsw[t*128 + lane];
            bl.u = wsw[t*128 + 64 + lane];
            a = __builtin_amdgcn_mfma_f32_16x16x32_bf16(aH[ks], bh.b, a, 0, 0, 0);
            a = __builtin_amdgcn_mfma_f32_16x16x32_bf16(aH[ks], bl.b, a, 0, 0, 0);
            a = __builtin_amdgcn_mfma_f32_16x16x32_bf16(aL[ks], bh.b, a, 0, 0, 0);
        }
        acc[nt] = a;
    }
}

template<int NT>
__device__ __forceinline__ void gemm64(
    const unsigned short* aHi, const unsigned short* aLo,
    const uint4* __restrict__ wsw, int tbase, int row, int quad, int lane,
    f32x4* acc)
{
    gemm64s<NT, 72>(aHi, aLo, wsw, tbase, row, quad, lane, acc);
}

__device__ __forceinline__ void ln_gelu_pass(
    f32x4* acc, const float* __restrict__ bias, const float* __restrict__ wrow,
    float coordBase, float coordScale,
    const float* __restrict__ gg, const float* __restrict__ bb,
    unsigned short* aHi, unsigned short* aLo, int rbase, int quad, int li)
{
    float vals[4][4];
    float s1[4] = {0,0,0,0}, s2[4] = {0,0,0,0};
    #pragma unroll
    for (int nt = 0; nt < 4; ++nt) {
        int col = nt*16 + li;
        float bv = bias[col];
        float br = wrow[col];
        #pragma unroll
        for (int rg = 0; rg < 4; ++rg) {
            float coord = (coordBase + (float)(rbase + quad*4 + rg)) * coordScale;
            float v = acc[nt][rg] + fmaf(coord, br, bv);
            vals[nt][rg] = v;
            s1[rg] += v;
            s2[rg] = fmaf(v, v, s2[rg]);
        }
    }
    #pragma unroll
    for (int d = 1; d < 16; d <<= 1) {
        #pragma unroll
        for (int rg = 0; rg < 4; ++rg) {
            s1[rg] += __shfl_xor(s1[rg], d, 64);
            s2[rg] += __shfl_xor(s2[rg], d, 64);
        }
    }
    #pragma unroll
    for (int nt = 0; nt < 4; ++nt) {
        int col = nt*16 + li;
        float gv = gg[col], bev = bb[col];
        #pragma unroll
        for (int rg = 0; rg < 4; ++rg) {
            float mu   = s1[rg] * 0.015625f;
            float rstd = rsqrtf(s2[rg]*0.015625f - mu*mu + LN_EPS);
            float v = gelu_f(fmaf((vals[nt][rg] - mu)*rstd, gv, bev));
            int r = rbase + quad*4 + rg;
            unsigned short hv = f2bf(v);
            aHi[r*72 + col] = hv;
            aLo[r*72 + col] = f2bf(v - bf2f(hv));
        }
    }
}

__device__ __forceinline__ void mlp_body(
    unsigned short* aHi, unsigned short* aLo,
    const uint4* __restrict__ wsw,
    const float* __restrict__ w0row,
    const float* __restrict__ b0, const float* __restrict__ g0, const float* __restrict__ be0,
    const float* __restrict__ b1, const float* __restrict__ g1, const float* __restrict__ be1,
    const float* __restrict__ b2,
    float coordBase,
    float* __restrict__ outR, float* __restrict__ outI, int pixBase)
{
    int tid = threadIdx.x;
    int wv = __builtin_amdgcn_readfirstlane(tid >> 6);
    int lane = tid & 63, li = lane & 15, quad = lane >> 4;
    int rbase = wv*16;
    int row = rbase + li;
    f32x4 acc[6];

    gemm64<4>(aHi, aLo, wsw, 0, row, quad, lane, acc);
    ln_gelu_pass(acc, b0, w0row, coordBase, 1.0f/191.0f, g0, be0, aHi, aLo, rbase, quad, li);
    gemm64<4>(aHi, aLo, wsw, 8, row, quad, lane, acc);
    ln_gelu_pass(acc, b1, b1, 0.f, 0.f, g1, be1, aHi, aLo, rbase, quad, li);
    gemm64<6>(aHi, aLo, wsw, 16, row, quad, lane, acc);
    #pragma unroll
    for (int nt = 0; nt < 6; ++nt) {
        int j = nt*16 + li;
        float bv = b2[j];
        #pragma unroll
        for (int rg = 0; rg < 4; ++rg) {
            float v = acc[nt][rg] + bv;
            int pix = pixBase + rbase + quad*4 + rg;
            if (nt < 3) outR[pix*48 + j]        = v;
            else        outI[pix*48 + (j - 48)] = v;
        }
    }
}

// K1: W-basis MLP.  grid 4608 = (b*192+h)*3 + wq.
__global__ __launch_bounds__(256) void k1_mlp_w(
    const float* __restrict__ x, const float* __restrict__ W0full,
    const float* __restrict__ b0, const float* __restrict__ g0, const float* __restrict__ be0,
    const float* __restrict__ b1, const float* __restrict__ g1, const float* __restrict__ be1,
    const float* __restrict__ b2,
    const uint4* __restrict__ wsw,
    float* __restrict__ wb_r, float* __restrict__ wb_i)
{
    __shared__ unsigned short aHi[64*72];
    __shared__ unsigned short aLo[64*72];
    int tid = threadIdx.x;
    int wv = __builtin_amdgcn_readfirstlane(tid >> 6);
    int lane = tid & 63, li = lane & 15, quad = lane >> 4;
    int wq = blockIdx.x % 3;
    int bh = blockIdx.x / 3;
    int b = bh / 192, h = bh % 192;
    int w0 = wq * 64;
    int r = wv*16 + li;
    #pragma unroll
    for (int cc = 0; cc < 16; ++cc) {
        int c = cc*4 + quad;
        float v = x[((b*64 + c)*192 + h)*192 + (w0 + r)];
        unsigned short hv = f2bf(v);
        aHi[r*72 + c] = hv;
        aLo[r*72 + c] = f2bf(v - bf2f(hv));
    }
    mlp_body(aHi, aLo, wsw, W0full + 64*64, b0, g0, be0, b1, g1, be1, b2,
             (float)w0, wb_r, wb_i, bh*192 + w0);
}

// K3: H-basis MLP.  grid 1152 = (b*48+m)*3 + hq.  t layout (B,M2,H,C):
// A-staging is now fully-coalesced float4 row loads.
__global__ __launch_bounds__(256) void k3_mlp_h(
    const float* __restrict__ t_r, const float* __restrict__ W0full,
    const float* __restrict__ b0, const float* __restrict__ g0, const float* __restrict__ be0,
    const float* __restrict__ b1, const float* __restrict__ g1, const float* __restrict__ be1,
    const float* __restrict__ b2,
    const uint4* __restrict__ wsw,
    float* __restrict__ hb_r, float* __restrict__ hb_i)
{
    __shared__ unsigned short aHi[64*72];
    __shared__ unsigned short aLo[64*72];
    int tid = threadIdx.x;
    int wv = __builtin_amdgcn_readfirstlane(tid >> 6);
    int lane = tid & 63, li = lane & 15, quad = lane >> 4;
    int hq = blockIdx.x % 3;
    int bm = blockIdx.x / 3;
    int b = bm / 48, m = bm % 48;
    int h0 = hq * 64;
    int r = wv*16 + li;
    {
        const float4* tb = (const float4*)(t_r + ((b*48 + m)*192 + h0 + r)*64);
        #pragma unroll
        for (int q = 0; q < 4; ++q) {
            float4 v4 = tb[quad*4 + q];
            float vv[4] = {v4.x, v4.y, v4.z, v4.w};
            int k0 = quad*16 + q*4;
            #pragma unroll
            for (int e = 0; e < 4; ++e) {
                unsigned short hv = f2bf(vv[e]);
                aHi[r*72 + k0 + e] = hv;
                aLo[r*72 + k0 + e] = f2bf(vv[e] - bf2f(hv));
            }
        }
    }
    mlp_body(aHi, aLo, wsw, W0full + 64*64, b0, g0, be0, b1, g1, be1, b2,
             (float)h0, hb_r, hb_i, bm*192 + h0);
}

// ===========================================================================
// K2 (MFMA): per (b,h): T[c][m] = sum_w X[c][w]*WB[w][m].
// grid 1536 = b*192+h; out t stored (B,M2,H,C) via LDS transpose.
// ===========================================================================
__global__ __launch_bounds__(256) void k2_t(
    const float* __restrict__ x,
    const float* __restrict__ wb_r, const float* __restrict__ wb_i,
    float* __restrict__ t_r, float* __restrict__ t_i)
{
    __shared__ unsigned short aHi[64*72];
    __shared__ unsigned short aLo[64*72];
    __shared__ uint4 bfrag[1536];            // 12 tiles x [hi:64|lo@+768]
    float* cbuf = (float*)bfrag;             // 48*67 floats, alias after barrier
    int bh = blockIdx.x;
    int b = bh / 192, h = bh % 192;
    int tid = threadIdx.x;
    int wv = __builtin_amdgcn_readfirstlane(tid >> 6);
    int lane = tid & 63, li = lane & 15, quad = lane >> 4;
    int rbase = wv*16;
    int row = rbase + li;

    f32x4 acc[6];
    {
        f32x4 z = {0.f, 0.f, 0.f, 0.f};
        #pragma unroll
        for (int nt = 0; nt < 6; ++nt) acc[nt] = z;
    }
    union U { uint4 u; bf16x8 b8; };

    for (int w0 = 0; w0 < 192; w0 += 64) {
        if (w0) __syncthreads();             // bfrag WAR across chunks
        {
            const float4* srow = (const float4*)(x + ((b*64 + row)*192 + h)*192 + w0) + quad*4;
            #pragma unroll
            for (int q = 0; q < 4; ++q) {
                float4 v4 = srow[q];
                float vv[4] = {v4.x, v4.y, v4.z, v4.w};
                int k0 = quad*16 + q*4;
                #pragma unroll
                for (int e = 0; e < 4; ++e) {
                    unsigned short hv = f2bf(vv[e]);
                    aHi[row*72 + k0 + e] = hv;
                    aLo[row*72 + k0 + e] = f2bf(vv[e] - bf2f(hv));
                }
            }
        }
        for (int t = tid >> 6; t < 12; t += 4) {
            int nt = t >> 1, ks = t & 1;
            const float* src = (nt < 3) ? wb_r : wb_i;
            int col = (nt < 3 ? nt : nt - 3)*16 + li;
            const float* sp = src + (bh*192 + w0 + ks*32 + quad*8)*48 + col;
            unsigned hi8[8], lo8[8];
            #pragma unroll
            for (int j = 0; j < 8; ++j) {
                float v = sp[j*48];
                unsigned short hv = f2bf(v);
                hi8[j] = hv;
                lo8[j] = f2bf(v - bf2f(hv));
            }
            uint4 ph, pl;
            ph.x = hi8[0] | (hi8[1]<<16); ph.y = hi8[2] | (hi8[3]<<16);
            ph.z = hi8[4] | (hi8[5]<<16); ph.w = hi8[6] | (hi8[7]<<16);
            pl.x = lo8[0] | (lo8[1]<<16); pl.y = lo8[2] | (lo8[3]<<16);
            pl.z = lo8[4] | (lo8[5]<<16); pl.w = lo8[6] | (lo8[7]<<16);
            bfrag[t*64 + lane]       = ph;
            bfrag[768 + t*64 + lane] = pl;
        }
        __syncthreads();
        bf16x8 aH[2], aL[2];
        #pragma unroll
        for (int ks = 0; ks < 2; ++ks) {
            aH[ks] = *(const bf16x8*)&aHi[row*72 + ks*32 + quad*8];
            aL[ks] = *(const bf16x8*)&aLo[row*72 + ks*32 + quad*8];
        }
        #pragma unroll
        for (int nt = 0; nt < 6; ++nt) {
            f32x4 a = acc[nt];
            #pragma unroll
            for (int ks = 0; ks < 2; ++ks) {
                int t = nt*2 + ks;
                U bh_, bl_;
                bh_.u = bfrag[t*64 + lane];
                bl_.u = bfrag[768 + t*64 + lane];
                a = __builtin_amdgcn_mfma_f32_16x16x32_bf16(aH[ks], bh_.b8, a, 0, 0, 0);
                a = __builtin_amdgcn_mfma_f32_16x16x32_bf16(aH[ks], bl_.b8, a, 0, 0, 0);
                a = __builtin_amdgcn_mfma_f32_16x16x32_bf16(aL[ks], bh_.b8, a, 0, 0, 0);
            }
            acc[nt] = a;
        }
    }
    // ---- epilogue: LDS transpose -> coalesced stores in (B,M2,H,C)
    __syncthreads();                         // all bfrag reads done
    #pragma unroll
    for (int nt = 0; nt < 3; ++nt) {
        int m = nt*16 + li;
        #pragma unroll
        for (int rg = 0; rg < 4; ++rg) {
            int c = rbase + quad*4 + rg;
            cbuf[m*67 + c] = acc[nt][rg];
        }
    }
    __syncthreads();
    for (int idx = tid; idx < 3072; idx += 256) {
        int m = idx >> 6, c = idx & 63;
        t_r[((b*48 + m)*192 + h)*64 + c] = cbuf[m*67 + c];
    }
    __syncthreads();
    #pragma unroll
    for (int nt = 3; nt < 6; ++nt) {
        int m = (nt - 3)*16 + li;
        #pragma unroll
        for (int rg = 0; rg < 4; ++rg) {
            int c = rbase + quad*4 + rg;
            cbuf[m*67 + c] = acc[nt][rg];
        }
    }
    __syncthreads();
    for (int idx = tid; idx < 3072; idx += 256) {
        int m = idx >> 6, c = idx & 63;
        t_i[((b*48 + m)*192 + h)*64 + c] = cbuf[m*67 + c];
    }
}

// ===========================================================================
// K4 (MFMA): per (b,m): T2[c][n] = sum_h T[c][h]*HB[h][n] (complex).
// t layout (B,M2,H,C) -> A-staging coalesced.  grid 384 = b*48+m.
// ===========================================================================
__global__ __launch_bounds__(256) void k4_t2(
    const float* __restrict__ t_r, const float* __restrict__ t_i,
    const float* __restrict__ hb_r, const float* __restrict__ hb_i,
    float* __restrict__ t2_r, float* __restrict__ t2_i)
{
    __shared__ unsigned short aHi[64*72];
    __shared__ unsigned short aLo[64*72];
    __shared__ uint4 bfrag[1536];
    int bm = blockIdx.x;
    int b = bm / 48, m = bm % 48;
    int tid = threadIdx.x;
    int wv = __builtin_amdgcn_readfirstlane(tid >> 6);
    int lane = tid & 63, li = lane & 15, quad = lane >> 4;
    int rbase = wv*16;
    int row = rbase + li;

    f32x4 acc[6];
    {
        f32x4 z = {0.f, 0.f, 0.f, 0.f};
        #pragma unroll
        for (int nt = 0; nt < 6; ++nt) acc[nt] = z;
    }
    union U { uint4 u; bf16x8 b8; };

    for (int p = 0; p < 6; ++p) {
        bool realp = (p < 3);
        int h0 = (p % 3) * 64;
        if (p) __syncthreads();
        // A chunk: rows c, k = h (coalesced: lanes over c, 64B per quad)
        {
            const float* tsrc = (realp ? t_r : t_i) + ((b*48 + m)*192 + h0)*64 + row;
            #pragma unroll
            for (int q = 0; q < 16; ++q) {
                int k = quad*16 + q;
                float v = tsrc[k*64];
                unsigned short hv = f2bf(v);
                aHi[row*72 + k] = hv;
                aLo[row*72 + k] = f2bf(v - bf2f(hv));
            }
        }
        // B chunk: 12 tiles from hb (with conj/sign structure)
        for (int t = tid >> 6; t < 12; t += 4) {
            int nt = t >> 1, ks = t & 1;
            const float* src;
            int col;
            float sgn = 1.f;
            if (realp) {
                if (nt < 3) { src = hb_r; col = nt*16 + li; }
                else        { src = hb_i; col = (nt - 3)*16 + li; }
            } else {
                if (nt < 3) { src = hb_i; col = nt*16 + li; sgn = -1.f; }
                else        { src = hb_r; col = (nt - 3)*16 + li; }
            }
            const float* sp = src + (bm*192 + h0 + ks*32 + quad*8)*48 + col;
            unsigned hi8[8], lo8[8];
            #pragma unroll
            for (int j = 0; j < 8; ++j) {
                float v = sgn * sp[j*48];
                unsigned short hv = f2bf(v);
                hi8[j] = hv;
                lo8[j] = f2bf(v - bf2f(hv));
            }
            uint4 ph, pl;
            ph.x = hi8[0] | (hi8[1]<<16); ph.y = hi8[2] | (hi8[3]<<16);
            ph.z = hi8[4] | (hi8[5]<<16); ph.w = hi8[6] | (hi8[7]<<16);
            pl.x = lo8[0] | (lo8[1]<<16); pl.y = lo8[2] | (lo8[3]<<16);
            pl.z = lo8[4] | (lo8[5]<<16); pl.w = lo8[6] | (lo8[7]<<16);
            bfrag[t*64 + lane]       = ph;
            bfrag[768 + t*64 + lane] = pl;
        }
        __syncthreads();
        bf16x8 aH[2], aL[2];
        #pragma unroll
        for (int ks = 0; ks < 2; ++ks) {
            aH[ks] = *(const bf16x8*)&aHi[row*72 + ks*32 + quad*8];
            aL[ks] = *(const bf16x8*)&aLo[row*72 + ks*32 + quad*8];
        }
        #pragma unroll
        for (int nt = 0; nt < 6; ++nt) {
            f32x4 a = acc[nt];
            #pragma unroll
            for (int ks = 0; ks < 2; ++ks) {
                int t = nt*2 + ks;
                U bh_, bl_;
                bh_.u = bfrag[t*64 + lane];
                bl_.u = bfrag[768 + t*64 + lane];
                a = __builtin_amdgcn_mfma_f32_16x16x32_bf16(aH[ks], bh_.b8, a, 0, 0, 0);
                a = __builtin_amdgcn_mfma_f32_16x16x32_bf16(aH[ks], bl_.b8, a, 0, 0, 0);
                a = __builtin_amdgcn_mfma_f32_16x16x32_bf16(aL[ks], bh_.b8, a, 0, 0, 0);
            }
            acc[nt] = a;
        }
    }
    // store in (B,C,N,M2)
    #pragma unroll
    for (int nt = 0; nt < 6; ++nt) {
        #pragma unroll
        for (int rg = 0; rg < 4; ++rg) {
            int c = rbase + quad*4 + rg;
            float v = acc[nt][rg];
            if (nt < 3) t2_r[((b*64 + c)*48 + nt*16 + li)*48 + m]       = v;
            else        t2_i[((b*64 + c)*48 + (nt - 3)*16 + li)*48 + m] = v;
        }
    }
}

// K5: proc[b,m,o,n] = sum_i t2[b,i,n,m]*Wf[o,i,n,m].  grid 288.
// proc now stored (B,M2,O,N) so k6's B-build reads are contiguous in n.
__global__ __launch_bounds__(256) void k5_proc(
    const float* __restrict__ t2_r, const float* __restrict__ t2_i,
    const float* __restrict__ fr, const float* __restrict__ fi,
    float* __restrict__ proc_r, float* __restrict__ proc_i)
{
    int og = blockIdx.x & 31;
    int ch = blockIdx.x >> 5;
    int nm = ch*256 + threadIdx.x;
    int n = nm / 48, mm = nm % 48;
    int o0 = og*2;
    float p0r[8], p0i[8], p1r[8], p1i[8];
    #pragma unroll
    for (int bb = 0; bb < 8; ++bb) { p0r[bb]=0.f; p0i[bb]=0.f; p1r[bb]=0.f; p1i[bb]=0.f; }
    for (int i = 0; i < 64; ++i) {
        float w0r = fr[(o0*64 + i)*2304 + nm];
        float w0i = fi[(o0*64 + i)*2304 + nm];
        float w1r = fr[((o0+1)*64 + i)*2304 + nm];
        float w1i = fi[((o0+1)*64 + i)*2304 + nm];
        #pragma unroll
        for (int bb = 0; bb < 8; ++bb) {
            float tr = t2_r[(bb*64 + i)*2304 + nm];
            float ti = t2_i[(bb*64 + i)*2304 + nm];
            p0r[bb] = fmaf(tr, w0r, fmaf(-ti, w0i, p0r[bb]));
            p0i[bb] = fmaf(tr, w0i, fmaf( ti, w0r, p0i[bb]));
            p1r[bb] = fmaf(tr, w1r, fmaf(-ti, w1i, p1r[bb]));
            p1i[bb] = fmaf(tr, w1i, fmaf( ti, w1r, p1i[bb]));
        }
    }
    #pragma unroll
    for (int bb = 0; bb < 8; ++bb) {
        int base0 = ((bb*48 + mm)*64 + o0)*48 + n;
        proc_r[base0]      = p0r[bb];
        proc_i[base0]      = p0i[bb];
        proc_r[base0 + 48] = p1r[bb];
        proc_i[base0 + 48] = p1i[bb];
    }
}

// ===========================================================================
// K6 (MFMA): rec_h[h][o] = sum_n proc[b,m,o,n]*conj-structure.
// proc (B,M2,O,N): every (ks,quad) is 8 contiguous n from one source ->
// two float4 loads per tile.  grid 1152 = bm*3 + hq.  rh stored (B,M2,H,O).
// ===========================================================================
__global__ __launch_bounds__(256) void k6_rech(
    const float* __restrict__ proc_r, const float* __restrict__ proc_i,
    const float* __restrict__ hb_r, const float* __restrict__ hb_i,
    float* __restrict__ rh_r, float* __restrict__ rh_i)
{
    __shared__ unsigned short aHi[64*104];
    __shared__ unsigned short aLo[64*104];
    __shared__ uint4 bfrag[1536];
    int hq = blockIdx.x % 3;
    int bm = blockIdx.x / 3;
    int b = bm / 48, m = bm % 48;
    int h0 = hq * 64;
    int tid = threadIdx.x;
    int wv = __builtin_amdgcn_readfirstlane(tid >> 6);
    int lane = tid & 63, li = lane & 15, quad = lane >> 4;
    int rbase = wv*16;
    int row = rbase + li;

    // A staging: hb row tile (64 h x 48r|48i) -> hi/lo bf16
    {
        int hr = bm*192 + h0 + row;
        const float4* pr = (const float4*)(hb_r + hr*48) + quad*3;
        const float4* pi = (const float4*)(hb_i + hr*48) + quad*3;
        #pragma unroll
        for (int q = 0; q < 3; ++q) {
            float4 vr = pr[q];
            float4 vi = pi[q];
            int k0 = quad*12 + q*4;
            float vs[8] = {vr.x, vr.y, vr.z, vr.w, vi.x, vi.y, vi.z, vi.w};
            #pragma unroll
            for (int e = 0; e < 4; ++e) {
                unsigned short h1 = f2bf(vs[e]);
                aHi[row*104 + k0 + e] = h1;
                aLo[row*104 + k0 + e] = f2bf(vs[e] - bf2f(h1));
                unsigned short h2 = f2bf(vs[4+e]);
                aHi[row*104 + 48 + k0 + e] = h2;
                aLo[row*104 + 48 + k0 + e] = f2bf(vs[4+e] - bf2f(h2));
            }
        }
    }
    union U { uint4 u; bf16x8 b8; };
    bf16x8 aH[3], aL[3];
    #pragma unroll
    for (int ks = 0; ks < 3; ++ks) {
        aH[ks] = *(const bf16x8*)&aHi[row*104 + ks*32 + quad*8];
        aL[ks] = *(const bf16x8*)&aLo[row*104 + ks*32 + quad*8];
    }

    f32x4 accR[4], accI[4];
    for (int pass = 0; pass < 2; ++pass) {
        if (pass) __syncthreads();           // bfrag WAR between passes
        for (int t = tid >> 6; t < 12; t += 4) {
            int ks = t % 3;
            int nt = t / 3;
            int o = nt*16 + li;
            int kk0 = ks*32 + quad*8;
            const float* srcp;
            int n0;
            float sgn;
            if (kk0 < 48) { srcp = pass ? proc_i : proc_r; n0 = kk0;      sgn = 1.f; }
            else          { srcp = pass ? proc_r : proc_i; n0 = kk0 - 48; sgn = pass ? -1.f : 1.f; }
            const float* sp = srcp + ((b*48 + m)*64 + o)*48 + n0;
            float4 f0 = *(const float4*)sp;
            float4 f1 = *(const float4*)(sp + 4);
            float vv[8] = {f0.x, f0.y, f0.z, f0.w, f1.x, f1.y, f1.z, f1.w};
            unsigned hi8[8], lo8[8];
            #pragma unroll
            for (int j = 0; j < 8; ++j) {
                float v = sgn * vv[j];
                unsigned short hv = f2bf(v);
                hi8[j] = hv;
                lo8[j] = f2bf(v - bf2f(hv));
            }
            uint4 ph, pl;
            ph.x = hi8[0] | (hi8[1]<<16); ph.y = hi8[2] | (hi8[3]<<16);
            ph.z = hi8[4] | (hi8[5]<<16); ph.w = hi8[6] | (hi8[7]<<16);
            pl.x = lo8[0] | (lo8[1]<<16); pl.y = lo8[2] | (lo8[3]<<16);
            pl.z = lo8[4] | (lo8[5]<<16); pl.w = lo8[6] | (lo8[7]<<16);
            bfrag[t*64 + lane]       = ph;
            bfrag[768 + t*64 + lane] = pl;
        }
        __syncthreads();
        f32x4* acc = pass ? accI : accR;
        #pragma unroll
        for (int nt = 0; nt < 4; ++nt) {
            f32x4 a = {0.f, 0.f, 0.f, 0.f};
            #pragma unroll
            for (int ks = 0; ks < 3; ++ks) {
                int t = nt*3 + ks;
                U bh_, bl_;
                bh_.u = bfrag[t*64 + lane];
                bl_.u = bfrag[768 + t*64 + lane];
                a = __builtin_amdgcn_mfma_f32_16x16x32_bf16(aH[ks], bh_.b8, a, 0, 0, 0);
                a = __builtin_amdgcn_mfma_f32_16x16x32_bf16(aH[ks], bl_.b8, a, 0, 0, 0);
                a = __builtin_amdgcn_mfma_f32_16x16x32_bf16(aL[ks], bh_.b8, a, 0, 0, 0);
            }
            acc[nt] = a;
        }
    }
    #pragma unroll
    for (int nt = 0; nt < 4; ++nt) {
        int o = nt*16 + li;
        #pragma unroll
        for (int rg = 0; rg < 4; ++rg) {
            int hrow = h0 + rbase + quad*4 + rg;
            int a = (bm*192 + hrow)*64 + o;
            rh_r[a] = accR[nt][rg];
            rh_i[a] = accI[nt][rg];
        }
    }
}

// ===========================================================================
// K7 (fused): inverse W-transform MFMA + mixer GEMM + channel-LN + GELU +
// shortcut GEMM + GELU.  grid 4608.
// ===========================================================================
__global__ __launch_bounds__(256) void k7_rec(
    const float* __restrict__ rh_r, const float* __restrict__ rh_i,
    const float* __restrict__ wb_r, const float* __restrict__ wb_i,
    const float* __restrict__ x,
    const uint4* __restrict__ msw,
    const float* __restrict__ mb,
    const float* __restrict__ nrm_g, const float* __restrict__ nrm_b,
    const float* __restrict__ sb,
    float* __restrict__ out)
{
    __shared__ unsigned short aHi[64*104];   // 64 rows x K=96 (+8 pad)
    __shared__ unsigned short aLo[64*104];
    __shared__ uint4 bfrag[1536];            // 12 tiles x [hi:64|lo@+768]
    float* cbuf = (float*)bfrag;             // alias, used after barrier

    int wq = blockIdx.x % 3;
    int bh = blockIdx.x / 3;
    int b = bh / 192, h = bh % 192;
    int w0 = wq * 64;
    int tid = threadIdx.x;
    int wv = __builtin_amdgcn_readfirstlane(tid >> 6);
    int lane = tid & 63, li = lane & 15, quad = lane >> 4;
    int rbase = wv*16;
    int row = rbase + li;

    // ---- A staging: wb tile (64 pix x 48 m, r then i) -> hi/lo bf16
    {
        int pix = bh*192 + w0 + row;
        const float4* pr = (const float4*)(wb_r + pix*48) + quad*3;
        const float4* pi = (const float4*)(wb_i + pix*48) + quad*3;
        #pragma unroll
        for (int q = 0; q < 3; ++q) {
            float4 vr = pr[q];
            float4 vi = pi[q];
            int k0 = quad*12 + q*4;
            float vs[8] = {vr.x, vr.y, vr.z, vr.w, vi.x, vi.y, vi.z, vi.w};
            #pragma unroll
            for (int e = 0; e < 4; ++e) {
                unsigned short h1 = f2bf(vs[e]);
                aHi[row*104 + k0 + e] = h1;
                aLo[row*104 + k0 + e] = f2bf(vs[e] - bf2f(h1));
                unsigned short h2 = f2bf(vs[4+e]);
                aHi[row*104 + 48 + k0 + e] = h2;
                aLo[row*104 + 48 + k0 + e] = f2bf(vs[4+e] - bf2f(h2));
            }
        }
    }
    // ---- B-fragment build: 12 tiles (t = nt*3 + ks)
    for (int t = tid >> 6; t < 12; t += 4) {
        int ks = t % 3;
        int nt = t / 3;
        int o = nt*16 + li;
        unsigned hi8[8], lo8[8];
        #pragma unroll
        for (int j = 0; j < 8; ++j) {
            int kk = ks*32 + quad*8 + j;
            const float* src = (kk < 48) ? rh_r : rh_i;
            int m = (kk < 48) ? kk : kk - 48;
            float v = src[((b*48 + m)*192 + h)*64 + o];
            unsigned short hv = f2bf(v);
            hi8[j] = hv;
            lo8[j] = f2bf(v - bf2f(hv));
        }
        uint4 ph, pl;
        ph.x = hi8[0] | (hi8[1]<<16); ph.y = hi8[2] | (hi8[3]<<16);
        ph.z = hi8[4] | (hi8[5]<<16); ph.w = hi8[6] | (hi8[7]<<16);
        pl.x = lo8[0] | (lo8[1]<<16); pl.y = lo8[2] | (lo8[3]<<16);
        pl.z = lo8[4] | (lo8[5]<<16); pl.w = lo8[6] | (lo8[7]<<16);
        bfrag[t*64 + lane]       = ph;
        bfrag[768 + t*64 + lane] = pl;
    }
    __syncthreads();

    // ---- k7 MFMA: y-tile (64 pix x 64 o) into acc
    union U { uint4 u; bf16x8 b; };
    bf16x8 aH[3], aL[3];
    #pragma unroll
    for (int ks = 0; ks < 3; ++ks) {
        aH[ks] = *(const bf16x8*)&aHi[row*104 + ks*32 + quad*8];
        aL[ks] = *(const bf16x8*)&aLo[row*104 + ks*32 + quad*8];
    }
    f32x4 acc[4];
    #pragma unroll
    for (int nt = 0; nt < 4; ++nt) {
        f32x4 a = {0.f, 0.f, 0.f, 0.f};
        #pragma unroll
        for (int ks = 0; ks < 3; ++ks) {
            int t = nt*3 + ks;
            U bh_, bl_;
            bh_.u = bfrag[t*64 + lane];
            bl_.u = bfrag[768 + t*64 + lane];
            a = __builtin_amdgcn_mfma_f32_16x16x32_bf16(aH[ks], bh_.b, a, 0, 0, 0);
            a = __builtin_amdgcn_mfma_f32_16x16x32_bf16(aH[ks], bl_.b, a, 0, 0, 0);
            a = __builtin_amdgcn_mfma_f32_16x16x32_bf16(aL[ks], bh_.b, a, 0, 0, 0);
        }
        acc[nt] = a;
    }

    // ---- mixer GEMM via wave-private LDS rows
    const float s = 1.0f / 36864.0f;
    #pragma unroll
    for (int nt = 0; nt < 4; ++nt) {
        int o = nt*16 + li;
        #pragma unroll
        for (int rg = 0; rg < 4; ++rg) {
            int prow = rbase + quad*4 + rg;
            float v = acc[nt][rg] * s;
            unsigned short hv = f2bf(v);
            aHi[prow*104 + o] = hv;
            aLo[prow*104 + o] = f2bf(v - bf2f(hv));
        }
    }
    f32x4 accy[4];
    gemm64s<4, 104>(aHi, aLo, msw, 0, row, quad, lane, accy);

    // ---- channel LN stats
    float vals[4][4];
    float s1[4] = {0,0,0,0}, s2[4] = {0,0,0,0};
    #pragma unroll
    for (int nt = 0; nt < 4; ++nt) {
        int o = nt*16 + li;
        float bv = mb[o];
        #pragma unroll
        for (int rg = 0; rg < 4; ++rg) {
            float v = accy[nt][rg] + bv;
            vals[nt][rg] = v;
            s1[rg] += v;
            s2[rg] = fmaf(v, v, s2[rg]);
        }
    }
    #pragma unroll
    for (int d = 1; d < 16; d <<= 1) {
        #pragma unroll
        for (int rg = 0; rg < 4; ++rg) {
            s1[rg] += __shfl_xor(s1[rg], d, 64);
            s2[rg] += __shfl_xor(s2[rg], d, 64);
        }
    }

    // ---- shortcut GEMM
    #pragma unroll
    for (int cc = 0; cc < 16; ++cc) {
        int c = cc*4 + quad;
        float v = x[((b*64 + c)*192 + h)*192 + w0 + row];
        unsigned short hv = f2bf(v);
        aHi[row*104 + c] = hv;
        aLo[row*104 + c] = f2bf(v - bf2f(hv));
    }
    gemm64s<4, 104>(aHi, aLo, msw, 8, row, quad, lane, acc);   // acc = shortcut

    __syncthreads();                       // all bfrag reads done; cbuf aliases
    #pragma unroll
    for (int nt = 0; nt < 4; ++nt) {
        int o = nt*16 + li;
        float gv = nrm_g[o], bev = nrm_b[o], sbv = sb[o];
        #pragma unroll
        for (int rg = 0; rg < 4; ++rg) {
            float mu   = s1[rg] * 0.015625f;
            float rstd = rsqrtf(s2[rg]*0.015625f - mu*mu + LN_EPS);
            float v  = gelu_f(fmaf((vals[nt][rg] - mu)*rstd, gv, bev));
            float sc = acc[nt][rg] + sbv;
            int prow = rbase + quad*4 + rg;
            cbuf[prow*67 + o] = gelu_f(v + sc);
        }
    }
    __syncthreads();
    #pragma unroll
    for (int it = 0; it < 16; ++it) {
        int o = it*4 + (tid >> 6);
        int pix = tid & 63;
        out[((b*64 + o)*192 + h)*192 + w0 + pix] = cbuf[pix*67 + o];
    }
}

extern "C" void kernel_launch(void* const* d_in, const int* in_sizes, int n_in,
                              void* d_out, int out_size, void* d_ws, size_t ws_size,
                              hipStream_t stream)
{
    (void)in_sizes; (void)n_in; (void)out_size; (void)ws_size;
    const float* x    = (const float*)d_in[0];
    const float* wW0  = (const float*)d_in[1];
    const float* wb0  = (const float*)d_in[2];
    const float* wg0  = (const float*)d_in[3];
    const float* wbe0 = (const float*)d_in[4];
    const float* wW1  = (const float*)d_in[5];
    const float* wb1  = (const float*)d_in[6];
    const float* wg1  = (const float*)d_in[7];
    const float* wbe1 = (const float*)d_in[8];
    const float* wW2  = (const float*)d_in[9];
    const float* wb2  = (const float*)d_in[10];
    const float* hW0  = (const float*)d_in[11];
    const float* hb0  = (const float*)d_in[12];
    const float* hg0  = (const float*)d_in[13];
    const float* hbe0 = (const float*)d_in[14];
    const float* hW1  = (const float*)d_in[15];
    const float* hb1  = (const float*)d_in[16];
    const float* hg1  = (const float*)d_in[17];
    const float* hbe1 = (const float*)d_in[18];
    const float* hW2  = (const float*)d_in[19];
    const float* hb2  = (const float*)d_in[20];
    const float* fr   = (const float*)d_in[21];
    const float* fi   = (const float*)d_in[22];
    const float* mw   = (const float*)d_in[23];
    const float* mb   = (const float*)d_in[24];
    const float* ngp  = (const float*)d_in[25];
    const float* nbp  = (const float*)d_in[26];
    const float* sw   = (const float*)d_in[27];
    const float* sb   = (const float*)d_in[28];
    float* out = (float*)d_out;

    float* ws   = (float*)d_ws;
    float* wbr  = ws;                  // 14,155,776  (B,H,W,M2)
    float* wbi  = ws + 14155776;
    float* t_r  = ws + 28311552;       //  4,718,592  (B,M2,H,C)
    float* t_i  = ws + 33030144;
    float* hbr  = ws + 37748736;       //  3,538,944  (B,M2,H,M1)
    float* hbi  = ws + 41287680;
    float* t2r  = ws + 44826624;       //  1,179,648  (B,C,N,M2); after k5: msw
    float* t2i  = ws + 46006272;
    float* prr  = ws + 47185920;       //  proc (B,M2,O,N)
    float* pri  = ws + 48365568;
    float* rhr  = t_r;                 // reuse: t dead after k4 -> rec_h (B,M2,H,O)
    float* rhi  = t_i;
    float* wswb = ws + 49545216;       // MLP weight fragments
    uint4* wsw  = (uint4*)wswb;
    uint4* msw  = (uint4*)t2r;         // mixer/shortcut weight fragments

    k0_swizzle<<<dim3(6), dim3(256), 0, stream>>>(wW0, wW1, wW2, hW0, hW1, hW2, wsw);
    k1_mlp_w<<<dim3(4608), dim3(256), 0, stream>>>(x, wW0, wb0, wg0, wbe0,
                                                   wb1, wg1, wbe1, wb2, wsw, wbr, wbi);
    k2_t<<<dim3(1536), dim3(256), 0, stream>>>(x, wbr, wbi, t_r, t_i);
    k3_mlp_h<<<dim3(1152), dim3(256), 0, stream>>>(t_r, hW0, hb0, hg0, hbe0,
                                                   hb1, hg1, hbe1, hb2, wsw + 3584, hbr, hbi);
    k4_t2<<<dim3(384), dim3(256), 0, stream>>>(t_r, t_i, hbr, hbi, t2r, t2i);
    k5_proc<<<dim3(288), dim3(256), 0, stream>>>(t2r, t2i, fr, fi, prr, pri);
    k0b_swizzle<<<dim3(2), dim3(256), 0, stream>>>(mw, sw, msw);   // t2 now dead
    k6_rech<<<dim3(1152), dim3(256), 0, stream>>>(prr, pri, hbr, hbi, rhr, rhi);
    k7_rec<<<dim3(4608), dim3(256), 0, stream>>>(rhr, rhi, wbr, wbi,
                                                 x, msw, mb, ngp, nbp, sb, out);
}